// Round 15
// baseline (610.687 us; speedup 1.0000x reference)
//
#include <hip/hip_runtime.h>
#include <math.h>

#define NHEADS 16
#define BBATCH 2
#define TSEQ   2048
#define HD     16
#define DIN    32
#define DST    64
#define CONVD  160
#define DPROJ  194
#define NHIN   2
#define DMODEL 256
#define CHUNK  32
#define NCHUNK (TSEQ / CHUNK)                  // 64
#define NWG    (2 * NHEADS * BBATCH * NCHUNK)  // 4096 (k1)
#define NWG3   (NHEADS * BBATCH * NCHUNK)      // 2048 (k3 fused)
#define YS     36

struct TeamParams {
  const float *Win, *convw, *convb, *dtb, *Alog, *Dp, *nw, *Wout;
};

typedef __attribute__((ext_vector_type(4)))  _Float16 half4;
typedef __attribute__((ext_vector_type(8)))  _Float16 half8;
typedef __attribute__((ext_vector_type(16))) float    f32x16;

// fast silu: v_rcp_f32 (~1ulp) instead of precise divide; outputs hit f16 anyway
__device__ __forceinline__ float sigm(float v) {
  return __builtin_amdgcn_rcpf(1.0f + __expf(-v));
}

__device__ __forceinline__ half8 pack_h8(float4 a, float4 b) {
  half8 r;
  r[0] = (_Float16)a.x; r[1] = (_Float16)a.y; r[2] = (_Float16)a.z; r[3] = (_Float16)a.w;
  r[4] = (_Float16)b.x; r[5] = (_Float16)b.y; r[6] = (_Float16)b.z; r[7] = (_Float16)b.w;
  return r;
}
__device__ __forceinline__ half8 zero_h8() {
  half8 r;
#pragma unroll
  for (int i = 0; i < 8; ++i) r[i] = (_Float16)0.f;
  return r;
}
__device__ __forceinline__ half8 ld8(const _Float16* p) {
  const half4 a = *reinterpret_cast<const half4*>(p);
  const half4 b = *reinterpret_cast<const half4*>(p + 4);
  half8 r;
  r[0] = a[0]; r[1] = a[1]; r[2] = a[2]; r[3] = a[3];
  r[4] = b[0]; r[5] = b[1]; r[6] = b[2]; r[7] = b[3];
  return r;
}

// ---------------------------------------------------------------------------
// Prep: hoist all wg-invariant packing to global f16 tensors; zero counters.
// ---------------------------------------------------------------------------
__global__ __launch_bounds__(256)
void prep_kernel(const float* __restrict__ x, TeamParams tp0, TeamParams tp1,
                 _Float16* __restrict__ xH, _Float16* __restrict__ WcF,
                 _Float16* __restrict__ WzF, _Float16* __restrict__ WdtF,
                 _Float16* __restrict__ wnH, int* __restrict__ cnt)
{
  const int gid = blockIdx.x * 256 + threadIdx.x;
  const int gsz = gridDim.x * 256;
  if (gid < 2 * NHEADS * BBATCH) cnt[gid] = 0;
  for (int i = gid; i < (BBATCH * TSEQ * DMODEL) / 8; i += gsz) {
    const float4 a = *reinterpret_cast<const float4*>(&x[(size_t)i * 8]);
    const float4 b = *reinterpret_cast<const float4*>(&x[(size_t)i * 8 + 4]);
    *reinterpret_cast<half8*>(&xH[(size_t)i * 8]) = pack_h8(a, b);
  }
  for (int i = gid; i < 2 * NHEADS * 4 * CONVD * 2; i += gsz) {
    const int k8 = i & 1;
    const int r = i >> 1;
    const int ch = r % CONVD;
    const int tap = (r / CONVD) & 3;
    const int th = r / (CONVD * 4);
    const int team = th >> 4, h = th & 15;
    const TeamParams P = team ? tp1 : tp0;
    const float cw = P.convw[((size_t)h * CONVD + ch) * 4 + tap];
    const float* wp = &P.Win[((size_t)h * DPROJ + 32 + ch) * HD + k8 * 8];
    half8 v;
#pragma unroll
    for (int j = 0; j < 8; ++j) v[j] = (_Float16)(cw * wp[j]);
    *reinterpret_cast<half8*>(&WcF[(size_t)r * 16 + k8 * 8]) = v;
  }
  for (int i = gid; i < 2 * NHEADS * 32 * 2; i += gsz) {
    const int k8 = i & 1;
    const int r = i >> 1;
    const int row = r & 31;
    const int th = r >> 5;
    const int team = th >> 4, h = th & 15;
    const TeamParams P = team ? tp1 : tp0;
    const float* wp = &P.Win[((size_t)h * DPROJ + row) * HD + k8 * 8];
    half8 v;
#pragma unroll
    for (int j = 0; j < 8; ++j) v[j] = (_Float16)wp[j];
    *reinterpret_cast<half8*>(&WzF[(size_t)r * 16 + k8 * 8]) = v;
  }
  for (int i = gid; i < 2 * NHEADS * 2 * 2; i += gsz) {
    const int k8 = i & 1;
    const int r = i >> 1;
    const int row = r & 1;
    const int th = r >> 1;
    const int team = th >> 4, h = th & 15;
    const TeamParams P = team ? tp1 : tp0;
    const float* wp = &P.Win[((size_t)h * DPROJ + 192 + row) * HD + k8 * 8];
    half8 v;
#pragma unroll
    for (int j = 0; j < 8; ++j) v[j] = (_Float16)wp[j];
    *reinterpret_cast<half8*>(&WdtF[(size_t)r * 16 + k8 * 8]) = v;
  }
  for (int i = gid; i < 2 * NHEADS * HD * DIN / 8; i += gsz) {
    const int dn8 = (i & 3) * 8;
    const int o = (i >> 2) & 15;
    const int th = i >> 6;
    const int team = th >> 4, h = th & 15;
    const TeamParams P = team ? tp1 : tp0;
    half8 v;
#pragma unroll
    for (int j = 0; j < 8; ++j)
      v[j] = (_Float16)(P.Wout[((size_t)h * HD + o) * DIN + dn8 + j] * P.nw[h * DIN + dn8 + j]);
    *reinterpret_cast<half8*>(&wnH[((size_t)th * HD + o) * DIN + dn8]) = v;
  }
}

// ---------------------------------------------------------------------------
// K1: conv-fused in-proj MFMA + SSD chunk computation + EMBEDDED carry
// (last wg of each (team,h,b) slice performs the inter-chunk combine).
// ---------------------------------------------------------------------------
__global__ __launch_bounds__(256, 7)
void k1_proj_ssd(const _Float16* __restrict__ xH, const _Float16* __restrict__ WcF,
                 const _Float16* __restrict__ WdtF, TeamParams tp0, TeamParams tp1,
                 _Float16* __restrict__ Sg, float* __restrict__ Pbuf,
                 float2* __restrict__ cumsg, _Float16* __restrict__ xgC,
                 _Float16* __restrict__ yintra, int* __restrict__ cnt)
{
  __shared__ _Float16 xvT[32][36];
  __shared__ _Float16 BmT[64][36];
  __shared__ _Float16 bufA[2][32][36];   // ph1-2: actB ; ph3+: Gm
  __shared__ _Float16 bufB[32][68];      // ph1-2: actC ; ph4: StL
  __shared__ _Float16 XtL[32][36];
  __shared__ _Float16 WXt[32][36];
  __shared__ float    dtraw[32][2];
  __shared__ float    clL[2][32], dtL2[2][32], dwL[2][32];
  __shared__ int      lastFlag;

  _Float16 (*actB)[68] = reinterpret_cast<_Float16(*)[68]>(&bufA[0][0][0]);
  _Float16 (*actC)[68] = bufB;
  _Float16 (*Gm)[32][36] = bufA;
  _Float16 (*StL)[68] = bufB;

  const int tid  = threadIdx.x;
  const int wg   = blockIdx.x;
  const int c    = wg % NCHUNK;
  const int b    = (wg / NCHUNK) % BBATCH;
  const int h    = (wg / (NCHUNK * BBATCH)) % NHEADS;
  const int team = wg / (NCHUNK * BBATCH * NHEADS);
  const TeamParams P = team ? tp1 : tp0;
  const int th = team * NHEADS + h;
  const int c0 = c * CHUNK;
  const size_t base0 = ((size_t)team * NHEADS + h) * BBATCH + b;

  const int lane = tid & 63;
  const int wv   = tid >> 6;
  const int lrow = lane & 31;
  const int kg   = lane >> 5;

  f32x16 z16;
#pragma unroll
  for (int i = 0; i < 16; ++i) z16[i] = 0.0f;
  f32x16 g = z16;

  half8 afr[4];
#pragma unroll
  for (int j = 0; j < 4; ++j) {
    const int tp = c0 + lrow - 3 + j;
    afr[j] = (tp >= 0)
        ? *reinterpret_cast<const half8*>(&xH[((size_t)b * TSEQ + tp) * DMODEL + h * HD + kg * 8])
        : zero_h8();
  }

  auto doTile = [&](int tile) {
    const int ch = tile * 32 + lrow;
    const float cb = P.convb[h * CONVD + ch];
    f32x16 acc = z16;
#pragma unroll
    for (int j = 0; j < 4; ++j) {
      const half8 bf = *reinterpret_cast<const half8*>(
          &WcF[((size_t)(th * 4 + j) * CONVD + ch) * 16 + kg * 8]);
      acc = __builtin_amdgcn_mfma_f32_32x32x16_f16(afr[j], bf, acc, 0, 0, 0);
    }
    _Float16 sv[16];
#pragma unroll
    for (int rg = 0; rg < 16; ++rg) {
      const float vv = acc[rg] + cb;
      sv[rg] = (_Float16)(vv * sigm(vv));
    }
    if (tile == 0) {
#pragma unroll
      for (int m = 0; m < 4; ++m) {
        half4 v; v[0] = sv[4*m]; v[1] = sv[4*m+1]; v[2] = sv[4*m+2]; v[3] = sv[4*m+3];
        *reinterpret_cast<half4*>(&xvT[lrow][4 * kg + 8 * m]) = v;
      }
    } else if (tile <= 2) {
      const int n = ch - 32;
#pragma unroll
      for (int m = 0; m < 4; ++m) {
        half4 v; v[0] = sv[4*m]; v[1] = sv[4*m+1]; v[2] = sv[4*m+2]; v[3] = sv[4*m+3];
        *reinterpret_cast<half4*>(&BmT[n][4 * kg + 8 * m]) = v;
      }
#pragma unroll
      for (int rg = 0; rg < 16; ++rg) {
        const int t = (rg & 3) + 8 * (rg >> 2) + 4 * kg;
        actB[t][n] = sv[rg];
      }
    } else {
      const int n = ch - 96;
#pragma unroll
      for (int rg = 0; rg < 16; ++rg) {
        const int t = (rg & 3) + 8 * (rg >> 2) + 4 * kg;
        actC[t][n] = sv[rg];
      }
    }
  };

  if (wv == 0) {
    doTile(0);
  } else if (wv == 1) {
    doTile(1);
  } else if (wv == 2) {
    doTile(2);
    half8 bf5 = zero_h8();
    if (lrow < 2)
      bf5 = *reinterpret_cast<const half8*>(&WdtF[((size_t)th * 2 + lrow) * 16 + kg * 8]);
    const f32x16 a5 = __builtin_amdgcn_mfma_f32_32x32x16_f16(afr[3], bf5, z16, 0, 0, 0);
    if (lrow < 2) {
#pragma unroll
      for (int rg = 0; rg < 16; ++rg) {
        const int t = (rg & 3) + 8 * (rg >> 2) + 4 * kg;
        dtraw[t][lrow] = a5[rg];
      }
    }
  } else {
    doTile(3);
    doTile(4);
  }
  __syncthreads();   // B1

  if (wv == 0) {
#pragma unroll
    for (int kk = 0; kk < 4; ++kk) {
      const half8 af = ld8(&actC[lrow][kk * 16 + kg * 8]);
      const half8 bf = ld8(&actB[lrow][kk * 16 + kg * 8]);
      g = __builtin_amdgcn_mfma_f32_32x32x16_f16(af, bf, g, 0, 0, 0);
    }
  } else if (wv == 1) {
    const int t = lane & 31, hi = lane >> 5;
    const float dtbias = P.dtb[h * NHIN + hi];
    const float Ah = -__expf(P.Alog[h * NHIN + hi]);
    const float raw = dtraw[t][hi] + dtbias;
    const float dtv = (raw > 20.f) ? raw : __logf(1.0f + __expf(raw));
    float s = dtv * Ah;
#pragma unroll
    for (int d = 1; d < 32; d <<= 1) {
      const float v = __shfl_up(s, d, 32);
      if (t >= d) s += v;
    }
    const float cl31 = __shfl(s, 31, 32);
    const float w = __expf(cl31 - s);
    const float ecl = __expf(s);
    clL[hi][t] = s;
    dtL2[hi][t] = dtv;
    dwL[hi][t] = w * dtv;
    const float eo = __shfl(ecl, (lane & 31) + 32, 64);
    if (lane < 32) cumsg[(size_t)wg * CHUNK + t] = make_float2(ecl, eo);
    if (t == 31) Pbuf[(base0 * NCHUNK + c) * NHIN + hi] = ecl;
  } else if (wv == 2) {
#pragma unroll
    for (int k = 0; k < 8; ++k) {
      const int idx = lane + k * 64;
      const int t = idx >> 4, c4 = (idx & 15) * 4;
      *reinterpret_cast<ushort4*>(&xgC[(size_t)wg * (CHUNK * DST) + t * DST + c4]) =
          *reinterpret_cast<const ushort4*>(&actC[t][c4]);
    }
  }
  __syncthreads();   // B2

  if (wv == 0) {
    const float cls0 = clL[0][lrow], cls1 = clL[1][lrow];
#pragma unroll
    for (int rg = 0; rg < 16; ++rg) {
      const int t = (rg & 3) + 8 * (rg >> 2) + 4 * kg;
      const float gg = g[rg];
      float l0 = 0.f, l1 = 0.f;
      if (lrow <= t) { l0 = __expf(clL[0][t] - cls0); l1 = __expf(clL[1][t] - cls1); }
      Gm[0][t][lrow] = (_Float16)(l0 * gg);
      Gm[1][t][lrow] = (_Float16)(l1 * gg);
    }
  } else if (wv == 1 || wv == 2) {
    const int idx = tid - 64;
    const int ch = idx & 31, tq = idx >> 5;
    const int hi = ch >> 4;
#pragma unroll
    for (int hh = 0; hh < 2; ++hh) {
      const int t4 = tq * 8 + hh * 4;
      const half4 xv4 = *reinterpret_cast<const half4*>(&xvT[ch][t4]);
      half4 xt, wx;
#pragma unroll
      for (int i = 0; i < 4; ++i) {
        const int t = t4 + i;
        const float xv = (float)xv4[i];
        xt[i] = (_Float16)(dtL2[hi][t] * xv);
        wx[i] = (_Float16)(dwL[hi][t] * xv);
      }
      *reinterpret_cast<half4*>(&XtL[ch][t4]) = xt;
      *reinterpret_cast<half4*>(&WXt[ch][t4]) = wx;
    }
  }
  __syncthreads();   // B3

  if (wv == 0 || wv == 3) {
    const int hi = (wv == 0) ? 0 : 1;
    const half8 xb0 = ld8(&XtL[lrow][kg * 8]);
    const half8 xb1 = ld8(&XtL[lrow][16 + kg * 8]);
    f32x16 acc = z16;
    acc = __builtin_amdgcn_mfma_f32_32x32x16_f16(ld8(&Gm[hi][lrow][kg * 8]), xb0, acc, 0, 0, 0);
    acc = __builtin_amdgcn_mfma_f32_32x32x16_f16(ld8(&Gm[hi][lrow][16 + kg * 8]), xb1, acc, 0, 0, 0);
    if ((lrow >> 4) == hi) {
      const float Dp = P.Dp[h * NHIN + hi];
      _Float16* yo = &yintra[(size_t)wg * (CHUNK * DIN)];
#pragma unroll
      for (int rg = 0; rg < 16; ++rg) {
        const int t = (rg & 3) + 8 * (rg >> 2) + 4 * kg;
        yo[t * DIN + lrow] = (_Float16)(acc[rg] + Dp * (float)xvT[lrow][t]);
      }
    }
  } else {
    const int nhalf = (wv - 1) * 32;
    const half8 wa0 = ld8(&WXt[lrow][kg * 8]);
    const half8 wa1 = ld8(&WXt[lrow][16 + kg * 8]);
    f32x16 acc = z16;
    acc = __builtin_amdgcn_mfma_f32_32x32x16_f16(
        wa0, ld8(&BmT[nhalf + lrow][kg * 8]), acc, 0, 0, 0);
    acc = __builtin_amdgcn_mfma_f32_32x32x16_f16(
        wa1, ld8(&BmT[nhalf + lrow][16 + kg * 8]), acc, 0, 0, 0);
#pragma unroll
    for (int rg = 0; rg < 16; ++rg) {
      const int m = (rg & 3) + 8 * (rg >> 2) + 4 * kg;
      StL[m][nhalf + lrow] = (_Float16)acc[rg];
    }
    const size_t base2 = (base0 * NCHUNK + c) * (NHIN * HD * DST);
#pragma unroll
    for (int k = 0; k < 4; ++k) {
      const int idx = lane + k * 64;
      const int row = idx >> 3, c4 = (idx & 7) * 4 + nhalf;
      *reinterpret_cast<ushort4*>(&Sg[base2 + row * DST + c4]) =
          *reinterpret_cast<const ushort4*>(&StL[row][c4]);
    }
  }

  // ======= embedded carry: last wg of this (team,h,b) slice combines =======
  __threadfence();           // make this wg's Sg/Pbuf stores device-visible
  __syncthreads();
  if (tid == 0) {
    const int old = atomicAdd(&cnt[(int)base0], 1);
    lastFlag = (old == NCHUNK - 1) ? 1 : 0;
  }
  __syncthreads();
  if (!lastFlag) return;
  __threadfence();           // acquire: see all other wgs' stores

  {
    const int off = tid * 8;            // 0..2040 over NHIN*HD*DST = 2048 states
    const int hi = off >> 10;
    float hc[8] = {0, 0, 0, 0, 0, 0, 0, 0};
    for (int cb = 0; cb < NCHUNK; cb += 8) {
      half8 a[8];
      float Pv[8];
#pragma unroll
      for (int j = 0; j < 8; ++j) {
        const size_t sb = (base0 * NCHUNK + cb + j) * (NHIN * HD * DST) + off;
        a[j] = *reinterpret_cast<const half8*>(&Sg[sb]);
        Pv[j] = Pbuf[(base0 * NCHUNK + cb + j) * NHIN + hi];
      }
#pragma unroll
      for (int j = 0; j < 8; ++j) {
        const size_t sb = (base0 * NCHUNK + cb + j) * (NHIN * HD * DST) + off;
        half8 o;
#pragma unroll
        for (int k = 0; k < 8; ++k) o[k] = (_Float16)hc[k];
        *reinterpret_cast<half8*>(&Sg[sb]) = o;
#pragma unroll
        for (int k = 0; k < 8; ++k) hc[k] = fmaf(Pv[j], hc[k], (float)a[j][k]);
      }
    }
  }
}

// ---------------------------------------------------------------------------
// K3 fused: C·H_in + z MFMAs, gate+rms (-> f16), MFMA out-proj, diff, stats.
// ---------------------------------------------------------------------------
__global__ __launch_bounds__(256)
void k3_fused(const _Float16* __restrict__ Sg, const float2* __restrict__ cumsg,
              const _Float16* __restrict__ xgC, const _Float16* __restrict__ xH,
              const _Float16* __restrict__ WzF, const _Float16* __restrict__ wnH,
              const _Float16* __restrict__ yintra, const float* __restrict__ lam,
              float* __restrict__ diffb, float2* __restrict__ pstat)
{
  __shared__ float    ysh[2][CHUNK][YS];
  __shared__ float    cums2[2][CHUNK][2];
  __shared__ _Float16 zsh[2][32][40];
  __shared__ _Float16 ygH[2][32][36];
  __shared__ float    youtL[2][CHUNK][20];
  __shared__ float    red2[8];

  const int tid  = threadIdx.x;
  const int wg   = blockIdx.x;
  const int c    = wg % NCHUNK;
  const int b    = (wg / NCHUNK) % BBATCH;
  const int h    = wg / (NCHUNK * BBATCH);
  const int c0 = c * CHUNK;
  const int lane = tid & 63;
  const int wv   = tid >> 6;
  const int lrow = lane & 31;
  const int kg   = lane >> 5;

  const size_t wgT0 = (((size_t)0 * NHEADS + h) * BBATCH + b) * NCHUNK + c;
  const size_t wgT1 = (((size_t)1 * NHEADS + h) * BBATCH + b) * NCHUNK + c;

  f32x16 acc;
  if (wv < 2) {
    const size_t wgT = wv ? wgT1 : wgT0;
    const _Float16* ca = &xgC[wgT * (CHUNK * DST) + (size_t)lrow * DST + kg * 8];
    const _Float16* hb = &Sg[wgT * (NHIN * HD * DST) + (size_t)lrow * DST + kg * 8];
#pragma unroll
    for (int i = 0; i < 16; ++i) acc[i] = 0.0f;
    acc = __builtin_amdgcn_mfma_f32_32x32x16_f16(
        *reinterpret_cast<const half8*>(ca), *reinterpret_cast<const half8*>(hb), acc, 0, 0, 0);
    acc = __builtin_amdgcn_mfma_f32_32x32x16_f16(
        *reinterpret_cast<const half8*>(ca + 16), *reinterpret_cast<const half8*>(hb + 16), acc, 0, 0, 0);
    acc = __builtin_amdgcn_mfma_f32_32x32x16_f16(
        *reinterpret_cast<const half8*>(ca + 32), *reinterpret_cast<const half8*>(hb + 32), acc, 0, 0, 0);
    acc = __builtin_amdgcn_mfma_f32_32x32x16_f16(
        *reinterpret_cast<const half8*>(ca + 48), *reinterpret_cast<const half8*>(hb + 48), acc, 0, 0, 0);
  } else {
    const int team = wv - 2;
    const int th = team * NHEADS + h;
    const half8 afr = *reinterpret_cast<const half8*>(
        &xH[((size_t)b * TSEQ + c0 + lrow) * DMODEL + h * HD + kg * 8]);
    const half8 bfr = *reinterpret_cast<const half8*>(
        &WzF[((size_t)th * 32 + lrow) * 16 + kg * 8]);
    f32x16 zacc;
#pragma unroll
    for (int i = 0; i < 16; ++i) zacc[i] = 0.0f;
    zacc = __builtin_amdgcn_mfma_f32_32x32x16_f16(afr, bfr, zacc, 0, 0, 0);
#pragma unroll
    for (int rg = 0; rg < 16; ++rg) {
      const int t = (rg & 3) + 8 * (rg >> 2) + 4 * kg;
      const float v = zacc[rg];
      zsh[team][t][lrow] = (_Float16)(v * sigm(v));
    }
  }

  {
    const int tm = tid >> 7, li = tid & 127;
    const int t = li >> 2, c8 = (li & 3) * 8;
    const size_t wgT = tm ? wgT1 : wgT0;
    const half8 v = *reinterpret_cast<const half8*>(&yintra[wgT * (CHUNK * DIN) + li * 8]);
#pragma unroll
    for (int j = 0; j < 8; ++j) ysh[tm][t][c8 + j] = (float)v[j];
  }
  if (tid < 64) {
    const int tm = tid >> 5, t = tid & 31;
    const size_t wgT = tm ? wgT1 : wgT0;
    const float2 v = cumsg[wgT * CHUNK + t];
    cums2[tm][t][0] = v.x; cums2[tm][t][1] = v.y;
  }
  __syncthreads();   // B1

  if (wv < 2) {
    const int team = wv;
    const int hi = lrow >> 4;
#pragma unroll
    for (int rg = 0; rg < 16; ++rg) {
      const int t = (rg & 3) + 8 * (rg >> 2) + 4 * kg;
      ysh[team][t][lrow] = fmaf(cums2[team][t][hi], acc[rg], ysh[team][t][lrow]);
    }
  }
  __syncthreads();   // B2

  {
    const int tm = tid >> 7, l = tid & 127;
    const int q = l & 3, tl = l >> 2;
    const int dn0 = q * 8;
    float yg[8];
    float ss = 0.0f;
#pragma unroll
    for (int j = 0; j < 8; ++j) {
      const float g = ysh[tm][tl][dn0 + j] * (float)zsh[tm][tl][dn0 + j];
      yg[j] = g;
      ss += g * g;
    }
    ss += __shfl_xor(ss, 1, 4);
    ss += __shfl_xor(ss, 2, 4);
    const float rms = rsqrtf(ss * (1.0f / DIN) + 1e-5f);
    half4 o0, o1;
#pragma unroll
    for (int j = 0; j < 4; ++j) o0[j] = (_Float16)(yg[j] * rms);
#pragma unroll
    for (int j = 0; j < 4; ++j) o1[j] = (_Float16)(yg[4 + j] * rms);
    *reinterpret_cast<half4*>(&ygH[tm][tl][dn0]) = o0;
    *reinterpret_cast<half4*>(&ygH[tm][tl][dn0 + 4]) = o1;
  }
  __syncthreads();   // B3

  if (wv < 2) {
    const int tm = wv;
    const int th2 = tm * NHEADS + h;
    const half8 af0 = ld8(&ygH[tm][lrow][kg * 8]);
    const half8 af1 = ld8(&ygH[tm][lrow][16 + kg * 8]);
    half8 bf0 = zero_h8(), bf1 = zero_h8();
    if (lrow < 16) {
      const _Float16* wp = &wnH[((size_t)th2 * HD + lrow) * DIN];
      bf0 = *reinterpret_cast<const half8*>(wp + kg * 8);
      bf1 = *reinterpret_cast<const half8*>(wp + 16 + kg * 8);
    }
    f32x16 oacc;
#pragma unroll
    for (int i = 0; i < 16; ++i) oacc[i] = 0.0f;
    oacc = __builtin_amdgcn_mfma_f32_32x32x16_f16(af0, bf0, oacc, 0, 0, 0);
    oacc = __builtin_amdgcn_mfma_f32_32x32x16_f16(af1, bf1, oacc, 0, 0, 0);
    if (lrow < 16) {
#pragma unroll
      for (int rg = 0; rg < 16; ++rg) {
        const int t = (rg & 3) + 8 * (rg >> 2) + 4 * kg;
        youtL[tm][t][lrow] = oacc[rg];
      }
    }
  }
  __syncthreads();   // B4

  float s = 0.0f, s2 = 0.0f;
  if (tid < 128) {
    const int t = tid >> 2, hd0 = (tid & 3) * 4;
    const float4 l4 = *reinterpret_cast<const float4*>(&lam[h * HD + hd0]);
    const float* y0 = &youtL[0][t][hd0];
    const float* y1 = &youtL[1][t][hd0];
    float4 d;
    d.x = y0[0] - l4.x * y1[0];
    d.y = y0[1] - l4.y * y1[1];
    d.z = y0[2] - l4.z * y1[2];
    d.w = y0[3] - l4.w * y1[3];
    *reinterpret_cast<float4*>(
        &diffb[(((size_t)(h * BBATCH + b)) * TSEQ + c0 + t) * HD + hd0]) = d;
    s = d.x + d.y + d.z + d.w;
    s2 = d.x * d.x + d.y * d.y + d.z * d.z + d.w * d.w;
  }
#pragma unroll
  for (int off = 1; off < 64; off <<= 1) {
    s += __shfl_xor(s, off);
    s2 += __shfl_xor(s2, off);
  }
  if (lane == 0) { red2[wv * 2] = s; red2[wv * 2 + 1] = s2; }
  __syncthreads();
  if (tid == 0) pstat[wg] = make_float2(red2[0] + red2[2], red2[1] + red2[3]);
}

// ---------------------------------------------------------------------------
// Final (MFMA): stats reduce + groupnorm-apply (f16) + [32x256]x[256x256]
// f16 MFMA GEMM + bias + residual.
// ---------------------------------------------------------------------------
#define NFW (BBATCH * (TSEQ / 32) * 2)   // 256
__global__ __launch_bounds__(256)
void final_mfma(const float* __restrict__ x, const float* __restrict__ diffb,
                const float2* __restrict__ pstat, const float* __restrict__ gnw,
                const float* __restrict__ gnb, const float* __restrict__ projw,
                const float* __restrict__ projb, float* __restrict__ out)
{
  __shared__ _Float16 ndH[32][268];
  __shared__ float statL[NHEADS][2];

  const int wg = blockIdx.x;
  const int chalf = wg & 1;
  const int tt = (wg >> 1) & 63;
  const int b = wg >> 7;
  const int t0 = tt * 32;
  const int tid = threadIdx.x;
  const int lane = tid & 63;
  const int wv = tid >> 6;

  {
    const int h = tid >> 4, k0 = tid & 15;
    float s = 0.0f, s2 = 0.0f;
    for (int k = k0; k < NCHUNK; k += 16) {
      const float2 v = pstat[((size_t)h * BBATCH + b) * NCHUNK + k];
      s += v.x; s2 += v.y;
    }
    s += __shfl_xor(s, 1, 16);  s2 += __shfl_xor(s2, 1, 16);
    s += __shfl_xor(s, 2, 16);  s2 += __shfl_xor(s2, 2, 16);
    s += __shfl_xor(s, 4, 16);  s2 += __shfl_xor(s2, 4, 16);
    s += __shfl_xor(s, 8, 16);  s2 += __shfl_xor(s2, 8, 16);
    if (k0 == 0) {
      const float inv = 1.0f / (TSEQ * HD);
      const float mean = s * inv;
      const float var = s2 * inv - mean * mean;
      statL[h][0] = mean;
      statL[h][1] = rsqrtf(var + 1e-5f);
    }
  }
  __syncthreads();

  {
    const int d = tid, h = d >> 4, hd = d & 15;
    const float mean = statL[h][0];
    const float rstd = statL[h][1];
    const float g = gnw[d];
    const float be = gnb[d];
    const float* dp = &diffb[((size_t)(h * BBATCH + b) * TSEQ + t0) * HD + hd];
#pragma unroll
    for (int t = 0; t < 32; ++t)
      ndH[t][d] = (_Float16)((dp[t * HD] - mean) * rstd * g + be);
  }
  __syncthreads();

  const int lrow = lane & 31, kg = lane >> 5;
  const int n0 = chalf * 128 + wv * 32;
  const int d = n0 + lrow;
  f32x16 acc;
#pragma unroll
  for (int i = 0; i < 16; ++i) acc[i] = 0.0f;
  const float* wp0 = &projw[(size_t)d * DMODEL + kg * 8];
#pragma unroll
  for (int kt = 0; kt < DMODEL; kt += 16) {
    const half8 af = ld8(&ndH[lrow][kt + kg * 8]);
    const half8 bf = pack_h8(*reinterpret_cast<const float4*>(wp0 + kt),
                             *reinterpret_cast<const float4*>(wp0 + kt + 4));
    acc = __builtin_amdgcn_mfma_f32_32x32x16_f16(af, bf, acc, 0, 0, 0);
  }

  const float pb = projb[d];
#pragma unroll
  for (int rg = 0; rg < 16; ++rg) {
    const int t = (rg & 3) + 8 * (rg >> 2) + 4 * kg;
    const size_t o = ((size_t)b * TSEQ + t0 + t) * DMODEL + d;
    out[o] = x[o] + pb + acc[rg];
  }
}

// ---------------------------------------------------------------------------
extern "C" void kernel_launch(void* const* d_in, const int* in_sizes, int n_in,
                              void* d_out, int out_size, void* d_ws, size_t ws_size,
                              hipStream_t stream)
{
  const float* x = (const float*)d_in[0];
  TeamParams tp0 { (const float*)d_in[1], (const float*)d_in[2], (const float*)d_in[3],
                   (const float*)d_in[4], (const float*)d_in[5], (const float*)d_in[6],
                   (const float*)d_in[7], (const float*)d_in[8] };
  TeamParams tp1 { (const float*)d_in[9], (const float*)d_in[10], (const float*)d_in[11],
                   (const float*)d_in[12], (const float*)d_in[13], (const float*)d_in[14],
                   (const float*)d_in[15], (const float*)d_in[16] };
  const float* lam   = (const float*)d_in[17];
  const float* gnw   = (const float*)d_in[18];
  const float* gnb   = (const float*)d_in[19];
  const float* projw = (const float*)d_in[20];
  const float* projb = (const float*)d_in[21];

  // ws layout (bytes):
  //   Sg      @ 0           16,777,216
  //   Pbuf    @ 16,777,216      32,768
  //   cumsg   @ 16,809,984   1,048,576
  //   xgC     @ 17,858,560  16,777,216
  //   yintra  @ 34,635,776   8,388,608
  //   diffb   @ 43,024,384   4,194,304
  //   pstat   @ 47,218,688      16,384
  //   xH      @ 47,235,072   2,097,152
  //   WcF     @ 49,332,224     655,360
  //   WzF     @ 49,987,584      32,768
  //   WdtF    @ 50,020,352       2,048
  //   wnH     @ 50,022,400      32,768
  //   cnt     @ 50,055,168         256   (total ~50.1 MB)
  char* wsb = (char*)d_ws;
  _Float16* Sg    = (_Float16*)wsb;
  float* Pbuf     = (float*)(wsb + 16777216);
  float2* cumsg   = (float2*)(wsb + 16809984);
  _Float16* xgC   = (_Float16*)(wsb + 17858560);
  _Float16* yintra= (_Float16*)(wsb + 34635776);
  float* diffb    = (float*)(wsb + 43024384);
  float2* pstat   = (float2*)(wsb + 47218688);
  _Float16* xH    = (_Float16*)(wsb + 47235072);
  _Float16* WcF   = (_Float16*)(wsb + 49332224);
  _Float16* WzF   = (_Float16*)(wsb + 49987584);
  _Float16* WdtF  = (_Float16*)(wsb + 50020352);
  _Float16* wnH   = (_Float16*)(wsb + 50022400);
  int* cnt        = (int*)(wsb + 50055168);

  prep_kernel<<<dim3(320), dim3(256), 0, stream>>>(x, tp0, tp1, xH, WcF, WzF, WdtF, wnH, cnt);
  k1_proj_ssd<<<dim3(NWG), dim3(256), 0, stream>>>(xH, WcF, WdtF, tp0, tp1, Sg, Pbuf, cumsg, xgC, yintra, cnt);
  k3_fused<<<dim3(NWG3), dim3(256), 0, stream>>>(Sg, cumsg, xgC, xH, WzF, wnH, yintra, lam, diffb, pstat);
  final_mfma<<<dim3(NFW), dim3(256), 0, stream>>>(
      x, diffb, pstat, gnw, gnb, projw, projb, (float*)d_out);
}

// Round 16
// 76.986 us; speedup vs baseline: 7.9324x; 7.9324x over previous
//
#include <hip/hip_runtime.h>
#include <math.h>

#define NHEADS 16
#define BBATCH 2
#define TSEQ   2048
#define HD     16
#define DIN    32
#define DST    64
#define CONVD  160
#define DPROJ  194
#define NHIN   2
#define DMODEL 256
#define CHUNK  32
#define NCHUNK (TSEQ / CHUNK)                  // 64
#define NWG    (2 * NHEADS * BBATCH * NCHUNK)  // 4096 (k1)
#define NWG3   (NHEADS * BBATCH * NCHUNK)      // 2048 (k3 fused)
#define YS     36

struct TeamParams {
  const float *Win, *convw, *convb, *dtb, *Alog, *Dp, *nw, *Wout;
};

typedef __attribute__((ext_vector_type(4)))  _Float16 half4;
typedef __attribute__((ext_vector_type(8)))  _Float16 half8;
typedef __attribute__((ext_vector_type(16))) float    f32x16;

// fast silu: v_rcp_f32 (~1ulp) instead of precise divide; outputs hit f16 anyway
__device__ __forceinline__ float sigm(float v) {
  return __builtin_amdgcn_rcpf(1.0f + __expf(-v));
}

__device__ __forceinline__ half8 pack_h8(float4 a, float4 b) {
  half8 r;
  r[0] = (_Float16)a.x; r[1] = (_Float16)a.y; r[2] = (_Float16)a.z; r[3] = (_Float16)a.w;
  r[4] = (_Float16)b.x; r[5] = (_Float16)b.y; r[6] = (_Float16)b.z; r[7] = (_Float16)b.w;
  return r;
}
__device__ __forceinline__ half8 zero_h8() {
  half8 r;
#pragma unroll
  for (int i = 0; i < 8; ++i) r[i] = (_Float16)0.f;
  return r;
}
__device__ __forceinline__ half8 ld8(const _Float16* p) {
  const half4 a = *reinterpret_cast<const half4*>(p);
  const half4 b = *reinterpret_cast<const half4*>(p + 4);
  half8 r;
  r[0] = a[0]; r[1] = a[1]; r[2] = a[2]; r[3] = a[3];
  r[4] = b[0]; r[5] = b[1]; r[6] = b[2]; r[7] = b[3];
  return r;
}

// ---------------------------------------------------------------------------
// Prep: hoist all wg-invariant packing to global f16 tensors.
// ---------------------------------------------------------------------------
__global__ __launch_bounds__(256)
void prep_kernel(const float* __restrict__ x, TeamParams tp0, TeamParams tp1,
                 _Float16* __restrict__ xH, _Float16* __restrict__ WcF,
                 _Float16* __restrict__ WzF, _Float16* __restrict__ WdtF,
                 _Float16* __restrict__ wnH)
{
  const int gid = blockIdx.x * 256 + threadIdx.x;
  const int gsz = gridDim.x * 256;
  for (int i = gid; i < (BBATCH * TSEQ * DMODEL) / 8; i += gsz) {
    const float4 a = *reinterpret_cast<const float4*>(&x[(size_t)i * 8]);
    const float4 b = *reinterpret_cast<const float4*>(&x[(size_t)i * 8 + 4]);
    *reinterpret_cast<half8*>(&xH[(size_t)i * 8]) = pack_h8(a, b);
  }
  for (int i = gid; i < 2 * NHEADS * 4 * CONVD * 2; i += gsz) {
    const int k8 = i & 1;
    const int r = i >> 1;
    const int ch = r % CONVD;
    const int tap = (r / CONVD) & 3;
    const int th = r / (CONVD * 4);
    const int team = th >> 4, h = th & 15;
    const TeamParams P = team ? tp1 : tp0;
    const float cw = P.convw[((size_t)h * CONVD + ch) * 4 + tap];
    const float* wp = &P.Win[((size_t)h * DPROJ + 32 + ch) * HD + k8 * 8];
    half8 v;
#pragma unroll
    for (int j = 0; j < 8; ++j) v[j] = (_Float16)(cw * wp[j]);
    *reinterpret_cast<half8*>(&WcF[(size_t)r * 16 + k8 * 8]) = v;
  }
  for (int i = gid; i < 2 * NHEADS * 32 * 2; i += gsz) {
    const int k8 = i & 1;
    const int r = i >> 1;
    const int row = r & 31;
    const int th = r >> 5;
    const int team = th >> 4, h = th & 15;
    const TeamParams P = team ? tp1 : tp0;
    const float* wp = &P.Win[((size_t)h * DPROJ + row) * HD + k8 * 8];
    half8 v;
#pragma unroll
    for (int j = 0; j < 8; ++j) v[j] = (_Float16)wp[j];
    *reinterpret_cast<half8*>(&WzF[(size_t)r * 16 + k8 * 8]) = v;
  }
  for (int i = gid; i < 2 * NHEADS * 2 * 2; i += gsz) {
    const int k8 = i & 1;
    const int r = i >> 1;
    const int row = r & 1;
    const int th = r >> 1;
    const int team = th >> 4, h = th & 15;
    const TeamParams P = team ? tp1 : tp0;
    const float* wp = &P.Win[((size_t)h * DPROJ + 192 + row) * HD + k8 * 8];
    half8 v;
#pragma unroll
    for (int j = 0; j < 8; ++j) v[j] = (_Float16)wp[j];
    *reinterpret_cast<half8*>(&WdtF[(size_t)r * 16 + k8 * 8]) = v;
  }
  for (int i = gid; i < 2 * NHEADS * HD * DIN / 8; i += gsz) {
    const int dn8 = (i & 3) * 8;
    const int o = (i >> 2) & 15;
    const int th = i >> 6;
    const int team = th >> 4, h = th & 15;
    const TeamParams P = team ? tp1 : tp0;
    half8 v;
#pragma unroll
    for (int j = 0; j < 8; ++j)
      v[j] = (_Float16)(P.Wout[((size_t)h * HD + o) * DIN + dn8 + j] * P.nw[h * DIN + dn8 + j]);
    *reinterpret_cast<half8*>(&wnH[((size_t)th * HD + o) * DIN + dn8]) = v;
  }
}

// ---------------------------------------------------------------------------
// K1: conv-fused in-proj MFMA + SSD chunk computation. LDS-aliased buffers,
// 3 barriers, wave-specialized phases. Phase-1 rebalanced (dt on wv2).
// ---------------------------------------------------------------------------
__global__ __launch_bounds__(256, 7)
void k1_proj_ssd(const _Float16* __restrict__ xH, const _Float16* __restrict__ WcF,
                 const _Float16* __restrict__ WdtF, TeamParams tp0, TeamParams tp1,
                 _Float16* __restrict__ Sg, float* __restrict__ Pbuf,
                 float2* __restrict__ cumsg, _Float16* __restrict__ xgC,
                 _Float16* __restrict__ yintra)
{
  __shared__ _Float16 xvT[32][36];
  __shared__ _Float16 BmT[64][36];
  __shared__ _Float16 bufA[2][32][36];   // ph1-2: actB ; ph3+: Gm
  __shared__ _Float16 bufB[32][68];      // ph1-2: actC ; ph4: StL
  __shared__ _Float16 XtL[32][36];
  __shared__ _Float16 WXt[32][36];
  __shared__ float    dtraw[32][2];
  __shared__ float    clL[2][32], dtL2[2][32], dwL[2][32];

  _Float16 (*actB)[68] = reinterpret_cast<_Float16(*)[68]>(&bufA[0][0][0]);
  _Float16 (*actC)[68] = bufB;
  _Float16 (*Gm)[32][36] = bufA;
  _Float16 (*StL)[68] = bufB;

  const int tid  = threadIdx.x;
  const int wg   = blockIdx.x;
  const int c    = wg % NCHUNK;
  const int b    = (wg / NCHUNK) % BBATCH;
  const int h    = (wg / (NCHUNK * BBATCH)) % NHEADS;
  const int team = wg / (NCHUNK * BBATCH * NHEADS);
  const TeamParams P = team ? tp1 : tp0;
  const int th = team * NHEADS + h;
  const int c0 = c * CHUNK;
  const size_t base0 = ((size_t)team * NHEADS + h) * BBATCH + b;

  const int lane = tid & 63;
  const int wv   = tid >> 6;
  const int lrow = lane & 31;
  const int kg   = lane >> 5;

  f32x16 z16;
#pragma unroll
  for (int i = 0; i < 16; ++i) z16[i] = 0.0f;
  f32x16 g = z16;

  half8 afr[4];
#pragma unroll
  for (int j = 0; j < 4; ++j) {
    const int tp = c0 + lrow - 3 + j;
    afr[j] = (tp >= 0)
        ? *reinterpret_cast<const half8*>(&xH[((size_t)b * TSEQ + tp) * DMODEL + h * HD + kg * 8])
        : zero_h8();
  }

  auto doTile = [&](int tile) {
    const int ch = tile * 32 + lrow;
    const float cb = P.convb[h * CONVD + ch];
    f32x16 acc = z16;
#pragma unroll
    for (int j = 0; j < 4; ++j) {
      const half8 bf = *reinterpret_cast<const half8*>(
          &WcF[((size_t)(th * 4 + j) * CONVD + ch) * 16 + kg * 8]);
      acc = __builtin_amdgcn_mfma_f32_32x32x16_f16(afr[j], bf, acc, 0, 0, 0);
    }
    _Float16 sv[16];
#pragma unroll
    for (int rg = 0; rg < 16; ++rg) {
      const float vv = acc[rg] + cb;
      sv[rg] = (_Float16)(vv * sigm(vv));
    }
    if (tile == 0) {
#pragma unroll
      for (int m = 0; m < 4; ++m) {
        half4 v; v[0] = sv[4*m]; v[1] = sv[4*m+1]; v[2] = sv[4*m+2]; v[3] = sv[4*m+3];
        *reinterpret_cast<half4*>(&xvT[lrow][4 * kg + 8 * m]) = v;
      }
    } else if (tile <= 2) {
      const int n = ch - 32;
#pragma unroll
      for (int m = 0; m < 4; ++m) {
        half4 v; v[0] = sv[4*m]; v[1] = sv[4*m+1]; v[2] = sv[4*m+2]; v[3] = sv[4*m+3];
        *reinterpret_cast<half4*>(&BmT[n][4 * kg + 8 * m]) = v;
      }
#pragma unroll
      for (int rg = 0; rg < 16; ++rg) {
        const int t = (rg & 3) + 8 * (rg >> 2) + 4 * kg;
        actB[t][n] = sv[rg];
      }
    } else {
      const int n = ch - 96;
#pragma unroll
      for (int rg = 0; rg < 16; ++rg) {
        const int t = (rg & 3) + 8 * (rg >> 2) + 4 * kg;
        actC[t][n] = sv[rg];
      }
    }
  };

  if (wv == 0) {
    doTile(0);
  } else if (wv == 1) {
    doTile(1);
  } else if (wv == 2) {
    doTile(2);
    half8 bf5 = zero_h8();
    if (lrow < 2)
      bf5 = *reinterpret_cast<const half8*>(&WdtF[((size_t)th * 2 + lrow) * 16 + kg * 8]);
    const f32x16 a5 = __builtin_amdgcn_mfma_f32_32x32x16_f16(afr[3], bf5, z16, 0, 0, 0);
    if (lrow < 2) {
#pragma unroll
      for (int rg = 0; rg < 16; ++rg) {
        const int t = (rg & 3) + 8 * (rg >> 2) + 4 * kg;
        dtraw[t][lrow] = a5[rg];
      }
    }
  } else {
    doTile(3);
    doTile(4);
  }
  __syncthreads();   // B1

  if (wv == 0) {
#pragma unroll
    for (int kk = 0; kk < 4; ++kk) {
      const half8 af = ld8(&actC[lrow][kk * 16 + kg * 8]);
      const half8 bf = ld8(&actB[lrow][kk * 16 + kg * 8]);
      g = __builtin_amdgcn_mfma_f32_32x32x16_f16(af, bf, g, 0, 0, 0);
    }
  } else if (wv == 1) {
    const int t = lane & 31, hi = lane >> 5;
    const float dtbias = P.dtb[h * NHIN + hi];
    const float Ah = -__expf(P.Alog[h * NHIN + hi]);
    const float raw = dtraw[t][hi] + dtbias;
    const float dtv = (raw > 20.f) ? raw : __logf(1.0f + __expf(raw));
    float s = dtv * Ah;
#pragma unroll
    for (int d = 1; d < 32; d <<= 1) {
      const float v = __shfl_up(s, d, 32);
      if (t >= d) s += v;
    }
    const float cl31 = __shfl(s, 31, 32);
    const float w = __expf(cl31 - s);
    const float ecl = __expf(s);
    clL[hi][t] = s;
    dtL2[hi][t] = dtv;
    dwL[hi][t] = w * dtv;
    const float eo = __shfl(ecl, (lane & 31) + 32, 64);
    if (lane < 32) cumsg[(size_t)wg * CHUNK + t] = make_float2(ecl, eo);
    if (t == 31) Pbuf[(base0 * NCHUNK + c) * NHIN + hi] = ecl;
  } else if (wv == 2) {
#pragma unroll
    for (int k = 0; k < 8; ++k) {
      const int idx = lane + k * 64;
      const int t = idx >> 4, c4 = (idx & 15) * 4;
      *reinterpret_cast<ushort4*>(&xgC[(size_t)wg * (CHUNK * DST) + t * DST + c4]) =
          *reinterpret_cast<const ushort4*>(&actC[t][c4]);
    }
  }
  __syncthreads();   // B2

  if (wv == 0) {
    const float cls0 = clL[0][lrow], cls1 = clL[1][lrow];
#pragma unroll
    for (int rg = 0; rg < 16; ++rg) {
      const int t = (rg & 3) + 8 * (rg >> 2) + 4 * kg;
      const float gg = g[rg];
      float l0 = 0.f, l1 = 0.f;
      if (lrow <= t) { l0 = __expf(clL[0][t] - cls0); l1 = __expf(clL[1][t] - cls1); }
      Gm[0][t][lrow] = (_Float16)(l0 * gg);
      Gm[1][t][lrow] = (_Float16)(l1 * gg);
    }
  } else if (wv == 1 || wv == 2) {
    const int idx = tid - 64;
    const int ch = idx & 31, tq = idx >> 5;
    const int hi = ch >> 4;
#pragma unroll
    for (int hh = 0; hh < 2; ++hh) {
      const int t4 = tq * 8 + hh * 4;
      const half4 xv4 = *reinterpret_cast<const half4*>(&xvT[ch][t4]);
      half4 xt, wx;
#pragma unroll
      for (int i = 0; i < 4; ++i) {
        const int t = t4 + i;
        const float xv = (float)xv4[i];
        xt[i] = (_Float16)(dtL2[hi][t] * xv);
        wx[i] = (_Float16)(dwL[hi][t] * xv);
      }
      *reinterpret_cast<half4*>(&XtL[ch][t4]) = xt;
      *reinterpret_cast<half4*>(&WXt[ch][t4]) = wx;
    }
  }
  __syncthreads();   // B3

  if (wv == 0 || wv == 3) {
    const int hi = (wv == 0) ? 0 : 1;
    const half8 xb0 = ld8(&XtL[lrow][kg * 8]);
    const half8 xb1 = ld8(&XtL[lrow][16 + kg * 8]);
    f32x16 acc = z16;
    acc = __builtin_amdgcn_mfma_f32_32x32x16_f16(ld8(&Gm[hi][lrow][kg * 8]), xb0, acc, 0, 0, 0);
    acc = __builtin_amdgcn_mfma_f32_32x32x16_f16(ld8(&Gm[hi][lrow][16 + kg * 8]), xb1, acc, 0, 0, 0);
    if ((lrow >> 4) == hi) {
      const float Dp = P.Dp[h * NHIN + hi];
      _Float16* yo = &yintra[(size_t)wg * (CHUNK * DIN)];
#pragma unroll
      for (int rg = 0; rg < 16; ++rg) {
        const int t = (rg & 3) + 8 * (rg >> 2) + 4 * kg;
        yo[t * DIN + lrow] = (_Float16)(acc[rg] + Dp * (float)xvT[lrow][t]);
      }
    }
  } else {
    const int nhalf = (wv - 1) * 32;
    const half8 wa0 = ld8(&WXt[lrow][kg * 8]);
    const half8 wa1 = ld8(&WXt[lrow][16 + kg * 8]);
    f32x16 acc = z16;
    acc = __builtin_amdgcn_mfma_f32_32x32x16_f16(
        wa0, ld8(&BmT[nhalf + lrow][kg * 8]), acc, 0, 0, 0);
    acc = __builtin_amdgcn_mfma_f32_32x32x16_f16(
        wa1, ld8(&BmT[nhalf + lrow][16 + kg * 8]), acc, 0, 0, 0);
#pragma unroll
    for (int rg = 0; rg < 16; ++rg) {
      const int m = (rg & 3) + 8 * (rg >> 2) + 4 * kg;
      StL[m][nhalf + lrow] = (_Float16)acc[rg];
    }
    const size_t base2 = (base0 * NCHUNK + c) * (NHIN * HD * DST);
#pragma unroll
    for (int k = 0; k < 4; ++k) {
      const int idx = lane + k * 64;
      const int row = idx >> 3, c4 = (idx & 7) * 4 + nhalf;
      *reinterpret_cast<ushort4*>(&Sg[base2 + row * DST + c4]) =
          *reinterpret_cast<const ushort4*>(&StL[row][c4]);
    }
  }
}

// ---------------------------------------------------------------------------
// Carry: 256 wgs x 64 threads; 8-deep prefetch.
// ---------------------------------------------------------------------------
__global__ __launch_bounds__(64)
void carry_kernel(_Float16* __restrict__ Sg, const float* __restrict__ Pbuf)
{
  const int wg = blockIdx.x;
  const int q = wg & 3;
  const int rest = wg >> 2;
  const int b = rest % BBATCH;
  const int h = (rest / BBATCH) % NHEADS;
  const int team = rest / (BBATCH * NHEADS);
  const int lane = threadIdx.x;
  const int off = q * 512 + lane * 8;
  const int hi = q >> 1;
  const size_t base0 = ((size_t)team * NHEADS + h) * BBATCH + b;

  float hc[8] = {0, 0, 0, 0, 0, 0, 0, 0};
  for (int cb = 0; cb < NCHUNK; cb += 8) {
    half8 a[8];
    float Pv[8];
#pragma unroll
    for (int j = 0; j < 8; ++j) {
      const size_t sb = (base0 * NCHUNK + cb + j) * (NHIN * HD * DST) + off;
      a[j] = *reinterpret_cast<const half8*>(&Sg[sb]);
      Pv[j] = Pbuf[(base0 * NCHUNK + cb + j) * NHIN + hi];
    }
#pragma unroll
    for (int j = 0; j < 8; ++j) {
      const size_t sb = (base0 * NCHUNK + cb + j) * (NHIN * HD * DST) + off;
      half8 o;
#pragma unroll
      for (int k = 0; k < 8; ++k) o[k] = (_Float16)hc[k];
      *reinterpret_cast<half8*>(&Sg[sb]) = o;
#pragma unroll
      for (int k = 0; k < 8; ++k) hc[k] = fmaf(Pv[j], hc[k], (float)a[j][k]);
    }
  }
}

// ---------------------------------------------------------------------------
// K3 fused: C·H_in + z MFMAs, gate+rms (-> f16), MFMA out-proj, diff, stats.
// ---------------------------------------------------------------------------
__global__ __launch_bounds__(256)
void k3_fused(const _Float16* __restrict__ Sg, const float2* __restrict__ cumsg,
              const _Float16* __restrict__ xgC, const _Float16* __restrict__ xH,
              const _Float16* __restrict__ WzF, const _Float16* __restrict__ wnH,
              const _Float16* __restrict__ yintra, const float* __restrict__ lam,
              float* __restrict__ diffb, float2* __restrict__ pstat)
{
  __shared__ float    ysh[2][CHUNK][YS];
  __shared__ float    cums2[2][CHUNK][2];
  __shared__ _Float16 zsh[2][32][40];
  __shared__ _Float16 ygH[2][32][36];
  __shared__ float    youtL[2][CHUNK][20];
  __shared__ float    red2[8];

  const int tid  = threadIdx.x;
  const int wg   = blockIdx.x;
  const int c    = wg % NCHUNK;
  const int b    = (wg / NCHUNK) % BBATCH;
  const int h    = wg / (NCHUNK * BBATCH);
  const int c0 = c * CHUNK;
  const int lane = tid & 63;
  const int wv   = tid >> 6;
  const int lrow = lane & 31;
  const int kg   = lane >> 5;

  const size_t wgT0 = (((size_t)0 * NHEADS + h) * BBATCH + b) * NCHUNK + c;
  const size_t wgT1 = (((size_t)1 * NHEADS + h) * BBATCH + b) * NCHUNK + c;

  f32x16 acc;
  if (wv < 2) {
    const size_t wgT = wv ? wgT1 : wgT0;
    const _Float16* ca = &xgC[wgT * (CHUNK * DST) + (size_t)lrow * DST + kg * 8];
    const _Float16* hb = &Sg[wgT * (NHIN * HD * DST) + (size_t)lrow * DST + kg * 8];
#pragma unroll
    for (int i = 0; i < 16; ++i) acc[i] = 0.0f;
    acc = __builtin_amdgcn_mfma_f32_32x32x16_f16(
        *reinterpret_cast<const half8*>(ca), *reinterpret_cast<const half8*>(hb), acc, 0, 0, 0);
    acc = __builtin_amdgcn_mfma_f32_32x32x16_f16(
        *reinterpret_cast<const half8*>(ca + 16), *reinterpret_cast<const half8*>(hb + 16), acc, 0, 0, 0);
    acc = __builtin_amdgcn_mfma_f32_32x32x16_f16(
        *reinterpret_cast<const half8*>(ca + 32), *reinterpret_cast<const half8*>(hb + 32), acc, 0, 0, 0);
    acc = __builtin_amdgcn_mfma_f32_32x32x16_f16(
        *reinterpret_cast<const half8*>(ca + 48), *reinterpret_cast<const half8*>(hb + 48), acc, 0, 0, 0);
  } else {
    const int team = wv - 2;
    const int th = team * NHEADS + h;
    const half8 afr = *reinterpret_cast<const half8*>(
        &xH[((size_t)b * TSEQ + c0 + lrow) * DMODEL + h * HD + kg * 8]);
    const half8 bfr = *reinterpret_cast<const half8*>(
        &WzF[((size_t)th * 32 + lrow) * 16 + kg * 8]);
    f32x16 zacc;
#pragma unroll
    for (int i = 0; i < 16; ++i) zacc[i] = 0.0f;
    zacc = __builtin_amdgcn_mfma_f32_32x32x16_f16(afr, bfr, zacc, 0, 0, 0);
#pragma unroll
    for (int rg = 0; rg < 16; ++rg) {
      const int t = (rg & 3) + 8 * (rg >> 2) + 4 * kg;
      const float v = zacc[rg];
      zsh[team][t][lrow] = (_Float16)(v * sigm(v));
    }
  }

  {
    const int tm = tid >> 7, li = tid & 127;
    const int t = li >> 2, c8 = (li & 3) * 8;
    const size_t wgT = tm ? wgT1 : wgT0;
    const half8 v = *reinterpret_cast<const half8*>(&yintra[wgT * (CHUNK * DIN) + li * 8]);
#pragma unroll
    for (int j = 0; j < 8; ++j) ysh[tm][t][c8 + j] = (float)v[j];
  }
  if (tid < 64) {
    const int tm = tid >> 5, t = tid & 31;
    const size_t wgT = tm ? wgT1 : wgT0;
    const float2 v = cumsg[wgT * CHUNK + t];
    cums2[tm][t][0] = v.x; cums2[tm][t][1] = v.y;
  }
  __syncthreads();   // B1

  if (wv < 2) {
    const int team = wv;
    const int hi = lrow >> 4;
#pragma unroll
    for (int rg = 0; rg < 16; ++rg) {
      const int t = (rg & 3) + 8 * (rg >> 2) + 4 * kg;
      ysh[team][t][lrow] = fmaf(cums2[team][t][hi], acc[rg], ysh[team][t][lrow]);
    }
  }
  __syncthreads();   // B2

  {
    const int tm = tid >> 7, l = tid & 127;
    const int q = l & 3, tl = l >> 2;
    const int dn0 = q * 8;
    float yg[8];
    float ss = 0.0f;
#pragma unroll
    for (int j = 0; j < 8; ++j) {
      const float g = ysh[tm][tl][dn0 + j] * (float)zsh[tm][tl][dn0 + j];
      yg[j] = g;
      ss += g * g;
    }
    ss += __shfl_xor(ss, 1, 4);
    ss += __shfl_xor(ss, 2, 4);
    const float rms = rsqrtf(ss * (1.0f / DIN) + 1e-5f);
    half4 o0, o1;
#pragma unroll
    for (int j = 0; j < 4; ++j) o0[j] = (_Float16)(yg[j] * rms);
#pragma unroll
    for (int j = 0; j < 4; ++j) o1[j] = (_Float16)(yg[4 + j] * rms);
    *reinterpret_cast<half4*>(&ygH[tm][tl][dn0]) = o0;
    *reinterpret_cast<half4*>(&ygH[tm][tl][dn0 + 4]) = o1;
  }
  __syncthreads();   // B3

  if (wv < 2) {
    const int tm = wv;
    const int th2 = tm * NHEADS + h;
    const half8 af0 = ld8(&ygH[tm][lrow][kg * 8]);
    const half8 af1 = ld8(&ygH[tm][lrow][16 + kg * 8]);
    half8 bf0 = zero_h8(), bf1 = zero_h8();
    if (lrow < 16) {
      const _Float16* wp = &wnH[((size_t)th2 * HD + lrow) * DIN];
      bf0 = *reinterpret_cast<const half8*>(wp + kg * 8);
      bf1 = *reinterpret_cast<const half8*>(wp + 16 + kg * 8);
    }
    f32x16 oacc;
#pragma unroll
    for (int i = 0; i < 16; ++i) oacc[i] = 0.0f;
    oacc = __builtin_amdgcn_mfma_f32_32x32x16_f16(af0, bf0, oacc, 0, 0, 0);
    oacc = __builtin_amdgcn_mfma_f32_32x32x16_f16(af1, bf1, oacc, 0, 0, 0);
    if (lrow < 16) {
#pragma unroll
      for (int rg = 0; rg < 16; ++rg) {
        const int t = (rg & 3) + 8 * (rg >> 2) + 4 * kg;
        youtL[tm][t][lrow] = oacc[rg];
      }
    }
  }
  __syncthreads();   // B4

  float s = 0.0f, s2 = 0.0f;
  if (tid < 128) {
    const int t = tid >> 2, hd0 = (tid & 3) * 4;
    const float4 l4 = *reinterpret_cast<const float4*>(&lam[h * HD + hd0]);
    const float* y0 = &youtL[0][t][hd0];
    const float* y1 = &youtL[1][t][hd0];
    float4 d;
    d.x = y0[0] - l4.x * y1[0];
    d.y = y0[1] - l4.y * y1[1];
    d.z = y0[2] - l4.z * y1[2];
    d.w = y0[3] - l4.w * y1[3];
    *reinterpret_cast<float4*>(
        &diffb[(((size_t)(h * BBATCH + b)) * TSEQ + c0 + t) * HD + hd0]) = d;
    s = d.x + d.y + d.z + d.w;
    s2 = d.x * d.x + d.y * d.y + d.z * d.z + d.w * d.w;
  }
#pragma unroll
  for (int off = 1; off < 64; off <<= 1) {
    s += __shfl_xor(s, off);
    s2 += __shfl_xor(s2, off);
  }
  if (lane == 0) { red2[wv * 2] = s; red2[wv * 2 + 1] = s2; }
  __syncthreads();
  if (tid == 0) pstat[wg] = make_float2(red2[0] + red2[2], red2[1] + red2[3]);
}

// ---------------------------------------------------------------------------
// Final (MFMA): stats reduce + groupnorm-apply (f16) + [32x256]x[256x256]
// f16 MFMA GEMM + bias + residual.
// ---------------------------------------------------------------------------
#define NFW (BBATCH * (TSEQ / 32) * 2)   // 256
__global__ __launch_bounds__(256)
void final_mfma(const float* __restrict__ x, const float* __restrict__ diffb,
                const float2* __restrict__ pstat, const float* __restrict__ gnw,
                const float* __restrict__ gnb, const float* __restrict__ projw,
                const float* __restrict__ projb, float* __restrict__ out)
{
  __shared__ _Float16 ndH[32][268];
  __shared__ float statL[NHEADS][2];

  const int wg = blockIdx.x;
  const int chalf = wg & 1;
  const int tt = (wg >> 1) & 63;
  const int b = wg >> 7;
  const int t0 = tt * 32;
  const int tid = threadIdx.x;
  const int lane = tid & 63;
  const int wv = tid >> 6;

  {
    const int h = tid >> 4, k0 = tid & 15;
    float s = 0.0f, s2 = 0.0f;
    for (int k = k0; k < NCHUNK; k += 16) {
      const float2 v = pstat[((size_t)h * BBATCH + b) * NCHUNK + k];
      s += v.x; s2 += v.y;
    }
    s += __shfl_xor(s, 1, 16);  s2 += __shfl_xor(s2, 1, 16);
    s += __shfl_xor(s, 2, 16);  s2 += __shfl_xor(s2, 2, 16);
    s += __shfl_xor(s, 4, 16);  s2 += __shfl_xor(s2, 4, 16);
    s += __shfl_xor(s, 8, 16);  s2 += __shfl_xor(s2, 8, 16);
    if (k0 == 0) {
      const float inv = 1.0f / (TSEQ * HD);
      const float mean = s * inv;
      const float var = s2 * inv - mean * mean;
      statL[h][0] = mean;
      statL[h][1] = rsqrtf(var + 1e-5f);
    }
  }
  __syncthreads();

  {
    const int d = tid, h = d >> 4, hd = d & 15;
    const float mean = statL[h][0];
    const float rstd = statL[h][1];
    const float g = gnw[d];
    const float be = gnb[d];
    const float* dp = &diffb[((size_t)(h * BBATCH + b) * TSEQ + t0) * HD + hd];
#pragma unroll
    for (int t = 0; t < 32; ++t)
      ndH[t][d] = (_Float16)((dp[t * HD] - mean) * rstd * g + be);
  }
  __syncthreads();

  const int lrow = lane & 31, kg = lane >> 5;
  const int n0 = chalf * 128 + wv * 32;
  const int d = n0 + lrow;
  f32x16 acc;
#pragma unroll
  for (int i = 0; i < 16; ++i) acc[i] = 0.0f;
  const float* wp0 = &projw[(size_t)d * DMODEL + kg * 8];
#pragma unroll
  for (int kt = 0; kt < DMODEL; kt += 16) {
    const half8 af = ld8(&ndH[lrow][kt + kg * 8]);
    const half8 bf = pack_h8(*reinterpret_cast<const float4*>(wp0 + kt),
                             *reinterpret_cast<const float4*>(wp0 + kt + 4));
    acc = __builtin_amdgcn_mfma_f32_32x32x16_f16(af, bf, acc, 0, 0, 0);
  }

  const float pb = projb[d];
#pragma unroll
  for (int rg = 0; rg < 16; ++rg) {
    const int t = (rg & 3) + 8 * (rg >> 2) + 4 * kg;
    const size_t o = ((size_t)b * TSEQ + t0 + t) * DMODEL + d;
    out[o] = x[o] + pb + acc[rg];
  }
}

// ---------------------------------------------------------------------------
extern "C" void kernel_launch(void* const* d_in, const int* in_sizes, int n_in,
                              void* d_out, int out_size, void* d_ws, size_t ws_size,
                              hipStream_t stream)
{
  const float* x = (const float*)d_in[0];
  TeamParams tp0 { (const float*)d_in[1], (const float*)d_in[2], (const float*)d_in[3],
                   (const float*)d_in[4], (const float*)d_in[5], (const float*)d_in[6],
                   (const float*)d_in[7], (const float*)d_in[8] };
  TeamParams tp1 { (const float*)d_in[9], (const float*)d_in[10], (const float*)d_in[11],
                   (const float*)d_in[12], (const float*)d_in[13], (const float*)d_in[14],
                   (const float*)d_in[15], (const float*)d_in[16] };
  const float* lam   = (const float*)d_in[17];
  const float* gnw   = (const float*)d_in[18];
  const float* gnb   = (const float*)d_in[19];
  const float* projw = (const float*)d_in[20];
  const float* projb = (const float*)d_in[21];

  // ws layout (bytes):
  //   Sg      @ 0           16,777,216
  //   Pbuf    @ 16,777,216      32,768
  //   cumsg   @ 16,809,984   1,048,576
  //   xgC     @ 17,858,560  16,777,216
  //   yintra  @ 34,635,776   8,388,608
  //   diffb   @ 43,024,384   4,194,304
  //   pstat   @ 47,218,688      16,384
  //   xH      @ 47,235,072   2,097,152
  //   WcF     @ 49,332,224     655,360
  //   WzF     @ 49,987,584      32,768
  //   WdtF    @ 50,020,352       2,048
  //   wnH     @ 50,022,400      32,768   (total ~50.1 MB)
  char* wsb = (char*)d_ws;
  _Float16* Sg    = (_Float16*)wsb;
  float* Pbuf     = (float*)(wsb + 16777216);
  float2* cumsg   = (float2*)(wsb + 16809984);
  _Float16* xgC   = (_Float16*)(wsb + 17858560);
  _Float16* yintra= (_Float16*)(wsb + 34635776);
  float* diffb    = (float*)(wsb + 43024384);
  float2* pstat   = (float2*)(wsb + 47218688);
  _Float16* xH    = (_Float16*)(wsb + 47235072);
  _Float16* WcF   = (_Float16*)(wsb + 49332224);
  _Float16* WzF   = (_Float16*)(wsb + 49987584);
  _Float16* WdtF  = (_Float16*)(wsb + 50020352);
  _Float16* wnH   = (_Float16*)(wsb + 50022400);

  prep_kernel<<<dim3(320), dim3(256), 0, stream>>>(x, tp0, tp1, xH, WcF, WzF, WdtF, wnH);
  k1_proj_ssd<<<dim3(NWG), dim3(256), 0, stream>>>(xH, WcF, WdtF, tp0, tp1, Sg, Pbuf, cumsg, xgC, yintra);
  carry_kernel<<<dim3(2 * NHEADS * BBATCH * 4), dim3(64), 0, stream>>>(Sg, Pbuf);
  k3_fused<<<dim3(NWG3), dim3(256), 0, stream>>>(Sg, cumsg, xgC, xH, WzF, wnH, yintra, lam, diffb, pstat);
  final_mfma<<<dim3(NFW), dim3(256), 0, stream>>>(
      x, diffb, pstat, gnw, gnb, projw, projb, (float*)d_out);
}

// Round 17
// 76.068 us; speedup vs baseline: 8.0282x; 1.0121x over previous
//
#include <hip/hip_runtime.h>
#include <math.h>

#define NHEADS 16
#define BBATCH 2
#define TSEQ   2048
#define HD     16
#define DIN    32
#define DST    64
#define CONVD  160
#define DPROJ  194
#define NHIN   2
#define DMODEL 256
#define CHUNK  32
#define NCHUNK (TSEQ / CHUNK)                  // 64
#define NWG    (2 * NHEADS * BBATCH * NCHUNK)  // 4096 (k1)
#define NWG3   (NHEADS * BBATCH * NCHUNK)      // 2048 (k3 fused)
#define YS     36

struct TeamParams {
  const float *Win, *convw, *convb, *dtb, *Alog, *Dp, *nw, *Wout;
};

typedef __attribute__((ext_vector_type(4)))  _Float16 half4;
typedef __attribute__((ext_vector_type(8)))  _Float16 half8;
typedef __attribute__((ext_vector_type(16))) float    f32x16;

// fast silu: v_rcp_f32 (~1ulp) instead of precise divide; outputs hit f16 anyway
__device__ __forceinline__ float sigm(float v) {
  return __builtin_amdgcn_rcpf(1.0f + __expf(-v));
}

__device__ __forceinline__ half8 pack_h8(float4 a, float4 b) {
  half8 r;
  r[0] = (_Float16)a.x; r[1] = (_Float16)a.y; r[2] = (_Float16)a.z; r[3] = (_Float16)a.w;
  r[4] = (_Float16)b.x; r[5] = (_Float16)b.y; r[6] = (_Float16)b.z; r[7] = (_Float16)b.w;
  return r;
}
__device__ __forceinline__ half8 zero_h8() {
  half8 r;
#pragma unroll
  for (int i = 0; i < 8; ++i) r[i] = (_Float16)0.f;
  return r;
}
__device__ __forceinline__ half8 ld8(const _Float16* p) {
  const half4 a = *reinterpret_cast<const half4*>(p);
  const half4 b = *reinterpret_cast<const half4*>(p + 4);
  half8 r;
  r[0] = a[0]; r[1] = a[1]; r[2] = a[2]; r[3] = a[3];
  r[4] = b[0]; r[5] = b[1]; r[6] = b[2]; r[7] = b[3];
  return r;
}

// ---------------------------------------------------------------------------
// Prep: hoist all wg-invariant packing to global f16 tensors.
// ---------------------------------------------------------------------------
__global__ __launch_bounds__(256)
void prep_kernel(const float* __restrict__ x, TeamParams tp0, TeamParams tp1,
                 _Float16* __restrict__ xH, _Float16* __restrict__ WcF,
                 _Float16* __restrict__ WzF, _Float16* __restrict__ WdtF,
                 _Float16* __restrict__ wnH)
{
  const int gid = blockIdx.x * 256 + threadIdx.x;
  const int gsz = gridDim.x * 256;
  for (int i = gid; i < (BBATCH * TSEQ * DMODEL) / 8; i += gsz) {
    const float4 a = *reinterpret_cast<const float4*>(&x[(size_t)i * 8]);
    const float4 b = *reinterpret_cast<const float4*>(&x[(size_t)i * 8 + 4]);
    *reinterpret_cast<half8*>(&xH[(size_t)i * 8]) = pack_h8(a, b);
  }
  for (int i = gid; i < 2 * NHEADS * 4 * CONVD * 2; i += gsz) {
    const int k8 = i & 1;
    const int r = i >> 1;
    const int ch = r % CONVD;
    const int tap = (r / CONVD) & 3;
    const int th = r / (CONVD * 4);
    const int team = th >> 4, h = th & 15;
    const TeamParams P = team ? tp1 : tp0;
    const float cw = P.convw[((size_t)h * CONVD + ch) * 4 + tap];
    const float* wp = &P.Win[((size_t)h * DPROJ + 32 + ch) * HD + k8 * 8];
    half8 v;
#pragma unroll
    for (int j = 0; j < 8; ++j) v[j] = (_Float16)(cw * wp[j]);
    *reinterpret_cast<half8*>(&WcF[(size_t)r * 16 + k8 * 8]) = v;
  }
  for (int i = gid; i < 2 * NHEADS * 32 * 2; i += gsz) {
    const int k8 = i & 1;
    const int r = i >> 1;
    const int row = r & 31;
    const int th = r >> 5;
    const int team = th >> 4, h = th & 15;
    const TeamParams P = team ? tp1 : tp0;
    const float* wp = &P.Win[((size_t)h * DPROJ + row) * HD + k8 * 8];
    half8 v;
#pragma unroll
    for (int j = 0; j < 8; ++j) v[j] = (_Float16)wp[j];
    *reinterpret_cast<half8*>(&WzF[(size_t)r * 16 + k8 * 8]) = v;
  }
  for (int i = gid; i < 2 * NHEADS * 2 * 2; i += gsz) {
    const int k8 = i & 1;
    const int r = i >> 1;
    const int row = r & 1;
    const int th = r >> 1;
    const int team = th >> 4, h = th & 15;
    const TeamParams P = team ? tp1 : tp0;
    const float* wp = &P.Win[((size_t)h * DPROJ + 192 + row) * HD + k8 * 8];
    half8 v;
#pragma unroll
    for (int j = 0; j < 8; ++j) v[j] = (_Float16)wp[j];
    *reinterpret_cast<half8*>(&WdtF[(size_t)r * 16 + k8 * 8]) = v;
  }
  for (int i = gid; i < 2 * NHEADS * HD * DIN / 8; i += gsz) {
    const int dn8 = (i & 3) * 8;
    const int o = (i >> 2) & 15;
    const int th = i >> 6;
    const int team = th >> 4, h = th & 15;
    const TeamParams P = team ? tp1 : tp0;
    half8 v;
#pragma unroll
    for (int j = 0; j < 8; ++j)
      v[j] = (_Float16)(P.Wout[((size_t)h * HD + o) * DIN + dn8 + j] * P.nw[h * DIN + dn8 + j]);
    *reinterpret_cast<half8*>(&wnH[((size_t)th * HD + o) * DIN + dn8]) = v;
  }
}

// ---------------------------------------------------------------------------
// K1: conv-fused in-proj MFMA + SSD chunk computation. LDS-aliased buffers,
// TWO barriers: scan runs wave-local in wv2's phase-1 tail; wv0 does G+mask
// back-to-back in phase 2.
// ---------------------------------------------------------------------------
__global__ __launch_bounds__(256, 7)
void k1_proj_ssd(const _Float16* __restrict__ xH, const _Float16* __restrict__ WcF,
                 const _Float16* __restrict__ WdtF, TeamParams tp0, TeamParams tp1,
                 _Float16* __restrict__ Sg, float* __restrict__ Pbuf,
                 float2* __restrict__ cumsg, _Float16* __restrict__ xgC,
                 _Float16* __restrict__ yintra)
{
  __shared__ _Float16 xvT[32][36];
  __shared__ _Float16 BmT[64][36];
  __shared__ _Float16 bufA[2][32][36];   // ph1-2: actB ; ph2(wv0-late)+: Gm
  __shared__ _Float16 bufB[32][68];      // ph1-2: actC ; ph3: StL
  __shared__ _Float16 XtL[32][36];
  __shared__ _Float16 WXt[32][36];
  __shared__ float    dtraw[32][2];
  __shared__ float    clL[2][32], dtL2[2][32], dwL[2][32];

  _Float16 (*actB)[68] = reinterpret_cast<_Float16(*)[68]>(&bufA[0][0][0]);
  _Float16 (*actC)[68] = bufB;
  _Float16 (*Gm)[32][36] = bufA;
  _Float16 (*StL)[68] = bufB;

  const int tid  = threadIdx.x;
  const int wg   = blockIdx.x;
  const int c    = wg % NCHUNK;
  const int b    = (wg / NCHUNK) % BBATCH;
  const int h    = (wg / (NCHUNK * BBATCH)) % NHEADS;
  const int team = wg / (NCHUNK * BBATCH * NHEADS);
  const TeamParams P = team ? tp1 : tp0;
  const int th = team * NHEADS + h;
  const int c0 = c * CHUNK;
  const size_t base0 = ((size_t)team * NHEADS + h) * BBATCH + b;

  const int lane = tid & 63;
  const int wv   = tid >> 6;
  const int lrow = lane & 31;
  const int kg   = lane >> 5;

  f32x16 z16;
#pragma unroll
  for (int i = 0; i < 16; ++i) z16[i] = 0.0f;

  half8 afr[4];
#pragma unroll
  for (int j = 0; j < 4; ++j) {
    const int tp = c0 + lrow - 3 + j;
    afr[j] = (tp >= 0)
        ? *reinterpret_cast<const half8*>(&xH[((size_t)b * TSEQ + tp) * DMODEL + h * HD + kg * 8])
        : zero_h8();
  }

  auto doTile = [&](int tile) {
    const int ch = tile * 32 + lrow;
    const float cb = P.convb[h * CONVD + ch];
    f32x16 acc = z16;
#pragma unroll
    for (int j = 0; j < 4; ++j) {
      const half8 bf = *reinterpret_cast<const half8*>(
          &WcF[((size_t)(th * 4 + j) * CONVD + ch) * 16 + kg * 8]);
      acc = __builtin_amdgcn_mfma_f32_32x32x16_f16(afr[j], bf, acc, 0, 0, 0);
    }
    _Float16 sv[16];
#pragma unroll
    for (int rg = 0; rg < 16; ++rg) {
      const float vv = acc[rg] + cb;
      sv[rg] = (_Float16)(vv * sigm(vv));
    }
    if (tile == 0) {
#pragma unroll
      for (int m = 0; m < 4; ++m) {
        half4 v; v[0] = sv[4*m]; v[1] = sv[4*m+1]; v[2] = sv[4*m+2]; v[3] = sv[4*m+3];
        *reinterpret_cast<half4*>(&xvT[lrow][4 * kg + 8 * m]) = v;
      }
    } else if (tile <= 2) {
      const int n = ch - 32;
#pragma unroll
      for (int m = 0; m < 4; ++m) {
        half4 v; v[0] = sv[4*m]; v[1] = sv[4*m+1]; v[2] = sv[4*m+2]; v[3] = sv[4*m+3];
        *reinterpret_cast<half4*>(&BmT[n][4 * kg + 8 * m]) = v;
      }
#pragma unroll
      for (int rg = 0; rg < 16; ++rg) {
        const int t = (rg & 3) + 8 * (rg >> 2) + 4 * kg;
        actB[t][n] = sv[rg];
      }
    } else {
      const int n = ch - 96;
#pragma unroll
      for (int rg = 0; rg < 16; ++rg) {
        const int t = (rg & 3) + 8 * (rg >> 2) + 4 * kg;
        actC[t][n] = sv[rg];
      }
    }
  };

  // ================= phase 1 ===============================================
  if (wv == 0) {
    doTile(0);
  } else if (wv == 1) {
    doTile(1);
  } else if (wv == 2) {
    doTile(2);
    // dt MFMA + wave-local scan (no cross-wave dependency)
    half8 bf5 = zero_h8();
    if (lrow < 2)
      bf5 = *reinterpret_cast<const half8*>(&WdtF[((size_t)th * 2 + lrow) * 16 + kg * 8]);
    const f32x16 a5 = __builtin_amdgcn_mfma_f32_32x32x16_f16(afr[3], bf5, z16, 0, 0, 0);
    if (lrow < 2) {
#pragma unroll
      for (int rg = 0; rg < 16; ++rg) {
        const int t = (rg & 3) + 8 * (rg >> 2) + 4 * kg;
        dtraw[t][lrow] = a5[rg];
      }
    }
    // same-wave LDS RAW: compiler inserts lgkmcnt wait; no barrier needed
    {
      const int t = lane & 31, hi = lane >> 5;
      const float dtbias = P.dtb[h * NHIN + hi];
      const float Ah = -__expf(P.Alog[h * NHIN + hi]);
      const float raw = dtraw[t][hi] + dtbias;
      const float dtv = (raw > 20.f) ? raw : __logf(1.0f + __expf(raw));
      float s = dtv * Ah;
#pragma unroll
      for (int d = 1; d < 32; d <<= 1) {
        const float v = __shfl_up(s, d, 32);
        if (t >= d) s += v;
      }
      const float cl31 = __shfl(s, 31, 32);
      const float w = __expf(cl31 - s);
      const float ecl = __expf(s);
      clL[hi][t] = s;
      dtL2[hi][t] = dtv;
      dwL[hi][t] = w * dtv;
      const float eo = __shfl(ecl, (lane & 31) + 32, 64);
      if (lane < 32) cumsg[(size_t)wg * CHUNK + t] = make_float2(ecl, eo);
      if (t == 31) Pbuf[(base0 * NCHUNK + c) * NHIN + hi] = ecl;
    }
  } else {
    doTile(3);
    doTile(4);
  }
  __syncthreads();   // B1

  // ================= phase 2 ===============================================
  if (wv == 0) {
    // G = C·B^T, then mask in the SAME wave (clL ready at B1)
    f32x16 g = z16;
#pragma unroll
    for (int kk = 0; kk < 4; ++kk) {
      const half8 af = ld8(&actC[lrow][kk * 16 + kg * 8]);
      const half8 bf = ld8(&actB[lrow][kk * 16 + kg * 8]);
      g = __builtin_amdgcn_mfma_f32_32x32x16_f16(af, bf, g, 0, 0, 0);
    }
    // Gm aliases actB: wv0 finished reading actB above (same-wave order safe)
    const float cls0 = clL[0][lrow], cls1 = clL[1][lrow];
#pragma unroll
    for (int rg = 0; rg < 16; ++rg) {
      const int t = (rg & 3) + 8 * (rg >> 2) + 4 * kg;
      const float gg = g[rg];
      float l0 = 0.f, l1 = 0.f;
      if (lrow <= t) { l0 = __expf(clL[0][t] - cls0); l1 = __expf(clL[1][t] - cls1); }
      Gm[0][t][lrow] = (_Float16)(l0 * gg);
      Gm[1][t][lrow] = (_Float16)(l1 * gg);
    }
  } else if (wv == 1 || wv == 2) {
    const int idx = tid - 64;
    const int ch = idx & 31, tq = idx >> 5;
    const int hi = ch >> 4;
#pragma unroll
    for (int hh = 0; hh < 2; ++hh) {
      const int t4 = tq * 8 + hh * 4;
      const half4 xv4 = *reinterpret_cast<const half4*>(&xvT[ch][t4]);
      half4 xt, wx;
#pragma unroll
      for (int i = 0; i < 4; ++i) {
        const int t = t4 + i;
        const float xv = (float)xv4[i];
        xt[i] = (_Float16)(dtL2[hi][t] * xv);
        wx[i] = (_Float16)(dwL[hi][t] * xv);
      }
      *reinterpret_cast<half4*>(&XtL[ch][t4]) = xt;
      *reinterpret_cast<half4*>(&WXt[ch][t4]) = wx;
    }
  } else {
    // wv3: xgC store (reads actC)
#pragma unroll
    for (int k = 0; k < 8; ++k) {
      const int idx = lane + k * 64;
      const int t = idx >> 4, c4 = (idx & 15) * 4;
      *reinterpret_cast<ushort4*>(&xgC[(size_t)wg * (CHUNK * DST) + t * DST + c4]) =
          *reinterpret_cast<const ushort4*>(&actC[t][c4]);
    }
  }
  __syncthreads();   // B2

  // ================= phase 3 ===============================================
  if (wv == 0 || wv == 3) {
    const int hi = (wv == 0) ? 0 : 1;
    const half8 xb0 = ld8(&XtL[lrow][kg * 8]);
    const half8 xb1 = ld8(&XtL[lrow][16 + kg * 8]);
    f32x16 acc = z16;
    acc = __builtin_amdgcn_mfma_f32_32x32x16_f16(ld8(&Gm[hi][lrow][kg * 8]), xb0, acc, 0, 0, 0);
    acc = __builtin_amdgcn_mfma_f32_32x32x16_f16(ld8(&Gm[hi][lrow][16 + kg * 8]), xb1, acc, 0, 0, 0);
    if ((lrow >> 4) == hi) {
      const float Dp = P.Dp[h * NHIN + hi];
      _Float16* yo = &yintra[(size_t)wg * (CHUNK * DIN)];
#pragma unroll
      for (int rg = 0; rg < 16; ++rg) {
        const int t = (rg & 3) + 8 * (rg >> 2) + 4 * kg;
        yo[t * DIN + lrow] = (_Float16)(acc[rg] + Dp * (float)xvT[lrow][t]);
      }
    }
  } else {
    const int nhalf = (wv - 1) * 32;
    const half8 wa0 = ld8(&WXt[lrow][kg * 8]);
    const half8 wa1 = ld8(&WXt[lrow][16 + kg * 8]);
    f32x16 acc = z16;
    acc = __builtin_amdgcn_mfma_f32_32x32x16_f16(
        wa0, ld8(&BmT[nhalf + lrow][kg * 8]), acc, 0, 0, 0);
    acc = __builtin_amdgcn_mfma_f32_32x32x16_f16(
        wa1, ld8(&BmT[nhalf + lrow][16 + kg * 8]), acc, 0, 0, 0);
#pragma unroll
    for (int rg = 0; rg < 16; ++rg) {
      const int m = (rg & 3) + 8 * (rg >> 2) + 4 * kg;
      StL[m][nhalf + lrow] = (_Float16)acc[rg];
    }
    // same-wave LDS RAW (own nhalf columns) -> no barrier needed
    const size_t base2 = (base0 * NCHUNK + c) * (NHIN * HD * DST);
#pragma unroll
    for (int k = 0; k < 4; ++k) {
      const int idx = lane + k * 64;
      const int row = idx >> 3, c4 = (idx & 7) * 4 + nhalf;
      *reinterpret_cast<ushort4*>(&Sg[base2 + row * DST + c4]) =
          *reinterpret_cast<const ushort4*>(&StL[row][c4]);
    }
  }
}

// ---------------------------------------------------------------------------
// Carry: 256 wgs x 64 threads; 8-deep prefetch.
// ---------------------------------------------------------------------------
__global__ __launch_bounds__(64)
void carry_kernel(_Float16* __restrict__ Sg, const float* __restrict__ Pbuf)
{
  const int wg = blockIdx.x;
  const int q = wg & 3;
  const int rest = wg >> 2;
  const int b = rest % BBATCH;
  const int h = (rest / BBATCH) % NHEADS;
  const int team = rest / (BBATCH * NHEADS);
  const int lane = threadIdx.x;
  const int off = q * 512 + lane * 8;
  const int hi = q >> 1;
  const size_t base0 = ((size_t)team * NHEADS + h) * BBATCH + b;

  float hc[8] = {0, 0, 0, 0, 0, 0, 0, 0};
  for (int cb = 0; cb < NCHUNK; cb += 8) {
    half8 a[8];
    float Pv[8];
#pragma unroll
    for (int j = 0; j < 8; ++j) {
      const size_t sb = (base0 * NCHUNK + cb + j) * (NHIN * HD * DST) + off;
      a[j] = *reinterpret_cast<const half8*>(&Sg[sb]);
      Pv[j] = Pbuf[(base0 * NCHUNK + cb + j) * NHIN + hi];
    }
#pragma unroll
    for (int j = 0; j < 8; ++j) {
      const size_t sb = (base0 * NCHUNK + cb + j) * (NHIN * HD * DST) + off;
      half8 o;
#pragma unroll
      for (int k = 0; k < 8; ++k) o[k] = (_Float16)hc[k];
      *reinterpret_cast<half8*>(&Sg[sb]) = o;
#pragma unroll
      for (int k = 0; k < 8; ++k) hc[k] = fmaf(Pv[j], hc[k], (float)a[j][k]);
    }
  }
}

// ---------------------------------------------------------------------------
// K3 fused: C·H_in + z MFMAs, gate+rms (-> f16), MFMA out-proj, diff, stats.
// ---------------------------------------------------------------------------
__global__ __launch_bounds__(256)
void k3_fused(const _Float16* __restrict__ Sg, const float2* __restrict__ cumsg,
              const _Float16* __restrict__ xgC, const _Float16* __restrict__ xH,
              const _Float16* __restrict__ WzF, const _Float16* __restrict__ wnH,
              const _Float16* __restrict__ yintra, const float* __restrict__ lam,
              float* __restrict__ diffb, float2* __restrict__ pstat)
{
  __shared__ float    ysh[2][CHUNK][YS];
  __shared__ float    cums2[2][CHUNK][2];
  __shared__ _Float16 zsh[2][32][40];
  __shared__ _Float16 ygH[2][32][36];
  __shared__ float    youtL[2][CHUNK][20];
  __shared__ float    red2[8];

  const int tid  = threadIdx.x;
  const int wg   = blockIdx.x;
  const int c    = wg % NCHUNK;
  const int b    = (wg / NCHUNK) % BBATCH;
  const int h    = wg / (NCHUNK * BBATCH);
  const int c0 = c * CHUNK;
  const int lane = tid & 63;
  const int wv   = tid >> 6;
  const int lrow = lane & 31;
  const int kg   = lane >> 5;

  const size_t wgT0 = (((size_t)0 * NHEADS + h) * BBATCH + b) * NCHUNK + c;
  const size_t wgT1 = (((size_t)1 * NHEADS + h) * BBATCH + b) * NCHUNK + c;

  f32x16 acc;
  if (wv < 2) {
    const size_t wgT = wv ? wgT1 : wgT0;
    const _Float16* ca = &xgC[wgT * (CHUNK * DST) + (size_t)lrow * DST + kg * 8];
    const _Float16* hb = &Sg[wgT * (NHIN * HD * DST) + (size_t)lrow * DST + kg * 8];
#pragma unroll
    for (int i = 0; i < 16; ++i) acc[i] = 0.0f;
    acc = __builtin_amdgcn_mfma_f32_32x32x16_f16(
        *reinterpret_cast<const half8*>(ca), *reinterpret_cast<const half8*>(hb), acc, 0, 0, 0);
    acc = __builtin_amdgcn_mfma_f32_32x32x16_f16(
        *reinterpret_cast<const half8*>(ca + 16), *reinterpret_cast<const half8*>(hb + 16), acc, 0, 0, 0);
    acc = __builtin_amdgcn_mfma_f32_32x32x16_f16(
        *reinterpret_cast<const half8*>(ca + 32), *reinterpret_cast<const half8*>(hb + 32), acc, 0, 0, 0);
    acc = __builtin_amdgcn_mfma_f32_32x32x16_f16(
        *reinterpret_cast<const half8*>(ca + 48), *reinterpret_cast<const half8*>(hb + 48), acc, 0, 0, 0);
  } else {
    const int team = wv - 2;
    const int th = team * NHEADS + h;
    const half8 afr = *reinterpret_cast<const half8*>(
        &xH[((size_t)b * TSEQ + c0 + lrow) * DMODEL + h * HD + kg * 8]);
    const half8 bfr = *reinterpret_cast<const half8*>(
        &WzF[((size_t)th * 32 + lrow) * 16 + kg * 8]);
    f32x16 zacc;
#pragma unroll
    for (int i = 0; i < 16; ++i) zacc[i] = 0.0f;
    zacc = __builtin_amdgcn_mfma_f32_32x32x16_f16(afr, bfr, zacc, 0, 0, 0);
#pragma unroll
    for (int rg = 0; rg < 16; ++rg) {
      const int t = (rg & 3) + 8 * (rg >> 2) + 4 * kg;
      const float v = zacc[rg];
      zsh[team][t][lrow] = (_Float16)(v * sigm(v));
    }
  }

  {
    const int tm = tid >> 7, li = tid & 127;
    const int t = li >> 2, c8 = (li & 3) * 8;
    const size_t wgT = tm ? wgT1 : wgT0;
    const half8 v = *reinterpret_cast<const half8*>(&yintra[wgT * (CHUNK * DIN) + li * 8]);
#pragma unroll
    for (int j = 0; j < 8; ++j) ysh[tm][t][c8 + j] = (float)v[j];
  }
  if (tid < 64) {
    const int tm = tid >> 5, t = tid & 31;
    const size_t wgT = tm ? wgT1 : wgT0;
    const float2 v = cumsg[wgT * CHUNK + t];
    cums2[tm][t][0] = v.x; cums2[tm][t][1] = v.y;
  }
  __syncthreads();   // B1

  if (wv < 2) {
    const int team = wv;
    const int hi = lrow >> 4;
#pragma unroll
    for (int rg = 0; rg < 16; ++rg) {
      const int t = (rg & 3) + 8 * (rg >> 2) + 4 * kg;
      ysh[team][t][lrow] = fmaf(cums2[team][t][hi], acc[rg], ysh[team][t][lrow]);
    }
  }
  __syncthreads();   // B2

  {
    const int tm = tid >> 7, l = tid & 127;
    const int q = l & 3, tl = l >> 2;
    const int dn0 = q * 8;
    float yg[8];
    float ss = 0.0f;
#pragma unroll
    for (int j = 0; j < 8; ++j) {
      const float g = ysh[tm][tl][dn0 + j] * (float)zsh[tm][tl][dn0 + j];
      yg[j] = g;
      ss += g * g;
    }
    ss += __shfl_xor(ss, 1, 4);
    ss += __shfl_xor(ss, 2, 4);
    const float rms = rsqrtf(ss * (1.0f / DIN) + 1e-5f);
    half4 o0, o1;
#pragma unroll
    for (int j = 0; j < 4; ++j) o0[j] = (_Float16)(yg[j] * rms);
#pragma unroll
    for (int j = 0; j < 4; ++j) o1[j] = (_Float16)(yg[4 + j] * rms);
    *reinterpret_cast<half4*>(&ygH[tm][tl][dn0]) = o0;
    *reinterpret_cast<half4*>(&ygH[tm][tl][dn0 + 4]) = o1;
  }
  __syncthreads();   // B3

  if (wv < 2) {
    const int tm = wv;
    const int th2 = tm * NHEADS + h;
    const half8 af0 = ld8(&ygH[tm][lrow][kg * 8]);
    const half8 af1 = ld8(&ygH[tm][lrow][16 + kg * 8]);
    half8 bf0 = zero_h8(), bf1 = zero_h8();
    if (lrow < 16) {
      const _Float16* wp = &wnH[((size_t)th2 * HD + lrow) * DIN];
      bf0 = *reinterpret_cast<const half8*>(wp + kg * 8);
      bf1 = *reinterpret_cast<const half8*>(wp + 16 + kg * 8);
    }
    f32x16 oacc;
#pragma unroll
    for (int i = 0; i < 16; ++i) oacc[i] = 0.0f;
    oacc = __builtin_amdgcn_mfma_f32_32x32x16_f16(af0, bf0, oacc, 0, 0, 0);
    oacc = __builtin_amdgcn_mfma_f32_32x32x16_f16(af1, bf1, oacc, 0, 0, 0);
    if (lrow < 16) {
#pragma unroll
      for (int rg = 0; rg < 16; ++rg) {
        const int t = (rg & 3) + 8 * (rg >> 2) + 4 * kg;
        youtL[tm][t][lrow] = oacc[rg];
      }
    }
  }
  __syncthreads();   // B4

  float s = 0.0f, s2 = 0.0f;
  if (tid < 128) {
    const int t = tid >> 2, hd0 = (tid & 3) * 4;
    const float4 l4 = *reinterpret_cast<const float4*>(&lam[h * HD + hd0]);
    const float* y0 = &youtL[0][t][hd0];
    const float* y1 = &youtL[1][t][hd0];
    float4 d;
    d.x = y0[0] - l4.x * y1[0];
    d.y = y0[1] - l4.y * y1[1];
    d.z = y0[2] - l4.z * y1[2];
    d.w = y0[3] - l4.w * y1[3];
    *reinterpret_cast<float4*>(
        &diffb[(((size_t)(h * BBATCH + b)) * TSEQ + c0 + t) * HD + hd0]) = d;
    s = d.x + d.y + d.z + d.w;
    s2 = d.x * d.x + d.y * d.y + d.z * d.z + d.w * d.w;
  }
#pragma unroll
  for (int off = 1; off < 64; off <<= 1) {
    s += __shfl_xor(s, off);
    s2 += __shfl_xor(s2, off);
  }
  if (lane == 0) { red2[wv * 2] = s; red2[wv * 2 + 1] = s2; }
  __syncthreads();
  if (tid == 0) pstat[wg] = make_float2(red2[0] + red2[2], red2[1] + red2[3]);
}

// ---------------------------------------------------------------------------
// Final (MFMA): stats reduce + groupnorm-apply (f16) + [32x256]x[256x256]
// f16 MFMA GEMM + bias + residual.
// ---------------------------------------------------------------------------
#define NFW (BBATCH * (TSEQ / 32) * 2)   // 256
__global__ __launch_bounds__(256)
void final_mfma(const float* __restrict__ x, const float* __restrict__ diffb,
                const float2* __restrict__ pstat, const float* __restrict__ gnw,
                const float* __restrict__ gnb, const float* __restrict__ projw,
                const float* __restrict__ projb, float* __restrict__ out)
{
  __shared__ _Float16 ndH[32][268];
  __shared__ float statL[NHEADS][2];

  const int wg = blockIdx.x;
  const int chalf = wg & 1;
  const int tt = (wg >> 1) & 63;
  const int b = wg >> 7;
  const int t0 = tt * 32;
  const int tid = threadIdx.x;
  const int lane = tid & 63;
  const int wv = tid >> 6;

  {
    const int h = tid >> 4, k0 = tid & 15;
    float s = 0.0f, s2 = 0.0f;
    for (int k = k0; k < NCHUNK; k += 16) {
      const float2 v = pstat[((size_t)h * BBATCH + b) * NCHUNK + k];
      s += v.x; s2 += v.y;
    }
    s += __shfl_xor(s, 1, 16);  s2 += __shfl_xor(s2, 1, 16);
    s += __shfl_xor(s, 2, 16);  s2 += __shfl_xor(s2, 2, 16);
    s += __shfl_xor(s, 4, 16);  s2 += __shfl_xor(s2, 4, 16);
    s += __shfl_xor(s, 8, 16);  s2 += __shfl_xor(s2, 8, 16);
    if (k0 == 0) {
      const float inv = 1.0f / (TSEQ * HD);
      const float mean = s * inv;
      const float var = s2 * inv - mean * mean;
      statL[h][0] = mean;
      statL[h][1] = rsqrtf(var + 1e-5f);
    }
  }
  __syncthreads();

  {
    const int d = tid, h = d >> 4, hd = d & 15;
    const float mean = statL[h][0];
    const float rstd = statL[h][1];
    const float g = gnw[d];
    const float be = gnb[d];
    const float* dp = &diffb[((size_t)(h * BBATCH + b) * TSEQ + t0) * HD + hd];
#pragma unroll
    for (int t = 0; t < 32; ++t)
      ndH[t][d] = (_Float16)((dp[t * HD] - mean) * rstd * g + be);
  }
  __syncthreads();

  const int lrow = lane & 31, kg = lane >> 5;
  const int n0 = chalf * 128 + wv * 32;
  const int d = n0 + lrow;
  f32x16 acc;
#pragma unroll
  for (int i = 0; i < 16; ++i) acc[i] = 0.0f;
  const float* wp0 = &projw[(size_t)d * DMODEL + kg * 8];
#pragma unroll
  for (int kt = 0; kt < DMODEL; kt += 16) {
    const half8 af = ld8(&ndH[lrow][kt + kg * 8]);
    const half8 bf = pack_h8(*reinterpret_cast<const float4*>(wp0 + kt),
                             *reinterpret_cast<const float4*>(wp0 + kt + 4));
    acc = __builtin_amdgcn_mfma_f32_32x32x16_f16(af, bf, acc, 0, 0, 0);
  }

  const float pb = projb[d];
#pragma unroll
  for (int rg = 0; rg < 16; ++rg) {
    const int t = (rg & 3) + 8 * (rg >> 2) + 4 * kg;
    const size_t o = ((size_t)b * TSEQ + t0 + t) * DMODEL + d;
    out[o] = x[o] + pb + acc[rg];
  }
}

// ---------------------------------------------------------------------------
extern "C" void kernel_launch(void* const* d_in, const int* in_sizes, int n_in,
                              void* d_out, int out_size, void* d_ws, size_t ws_size,
                              hipStream_t stream)
{
  const float* x = (const float*)d_in[0];
  TeamParams tp0 { (const float*)d_in[1], (const float*)d_in[2], (const float*)d_in[3],
                   (const float*)d_in[4], (const float*)d_in[5], (const float*)d_in[6],
                   (const float*)d_in[7], (const float*)d_in[8] };
  TeamParams tp1 { (const float*)d_in[9], (const float*)d_in[10], (const float*)d_in[11],
                   (const float*)d_in[12], (const float*)d_in[13], (const float*)d_in[14],
                   (const float*)d_in[15], (const float*)d_in[16] };
  const float* lam   = (const float*)d_in[17];
  const float* gnw   = (const float*)d_in[18];
  const float* gnb   = (const float*)d_in[19];
  const float* projw = (const float*)d_in[20];
  const float* projb = (const float*)d_in[21];

  // ws layout (bytes):
  //   Sg      @ 0           16,777,216
  //   Pbuf    @ 16,777,216      32,768
  //   cumsg   @ 16,809,984   1,048,576
  //   xgC     @ 17,858,560  16,777,216
  //   yintra  @ 34,635,776   8,388,608
  //   diffb   @ 43,024,384   4,194,304
  //   pstat   @ 47,218,688      16,384
  //   xH      @ 47,235,072   2,097,152
  //   WcF     @ 49,332,224     655,360
  //   WzF     @ 49,987,584      32,768
  //   WdtF    @ 50,020,352       2,048
  //   wnH     @ 50,022,400      32,768   (total ~50.1 MB)
  char* wsb = (char*)d_ws;
  _Float16* Sg    = (_Float16*)wsb;
  float* Pbuf     = (float*)(wsb + 16777216);
  float2* cumsg   = (float2*)(wsb + 16809984);
  _Float16* xgC   = (_Float16*)(wsb + 17858560);
  _Float16* yintra= (_Float16*)(wsb + 34635776);
  float* diffb    = (float*)(wsb + 43024384);
  float2* pstat   = (float2*)(wsb + 47218688);
  _Float16* xH    = (_Float16*)(wsb + 47235072);
  _Float16* WcF   = (_Float16*)(wsb + 49332224);
  _Float16* WzF   = (_Float16*)(wsb + 49987584);
  _Float16* WdtF  = (_Float16*)(wsb + 50020352);
  _Float16* wnH   = (_Float16*)(wsb + 50022400);

  prep_kernel<<<dim3(320), dim3(256), 0, stream>>>(x, tp0, tp1, xH, WcF, WzF, WdtF, wnH);
  k1_proj_ssd<<<dim3(NWG), dim3(256), 0, stream>>>(xH, WcF, WdtF, tp0, tp1, Sg, Pbuf, cumsg, xgC, yintra);
  carry_kernel<<<dim3(2 * NHEADS * BBATCH * 4), dim3(64), 0, stream>>>(Sg, Pbuf);
  k3_fused<<<dim3(NWG3), dim3(256), 0, stream>>>(Sg, cumsg, xgC, xH, WzF, wnH, yintra, lam, diffb, pstat);
  final_mfma<<<dim3(NFW), dim3(256), 0, stream>>>(
      x, diffb, pstat, gnw, gnb, projw, projb, (float*)d_out);
}

// Round 18
// 75.753 us; speedup vs baseline: 8.0615x; 1.0042x over previous
//
#include <hip/hip_runtime.h>
#include <math.h>

#define NHEADS 16
#define BBATCH 2
#define TSEQ   2048
#define HD     16
#define DIN    32
#define DST    64
#define CONVD  160
#define DPROJ  194
#define NHIN   2
#define DMODEL 256
#define CHUNK  32
#define NCHUNK (TSEQ / CHUNK)                  // 64
#define NWG    (2 * NHEADS * BBATCH * NCHUNK)  // 4096 (k1)
#define NWG3   (NHEADS * BBATCH * NCHUNK)      // 2048 (k3 fused)
#define YS     36

struct TeamParams {
  const float *Win, *convw, *convb, *dtb, *Alog, *Dp, *nw, *Wout;
};

typedef __attribute__((ext_vector_type(4)))  _Float16 half4;
typedef __attribute__((ext_vector_type(8)))  _Float16 half8;
typedef __attribute__((ext_vector_type(16))) float    f32x16;

// fast silu: v_rcp_f32 (~1ulp) instead of precise divide; outputs hit f16 anyway
__device__ __forceinline__ float sigm(float v) {
  return __builtin_amdgcn_rcpf(1.0f + __expf(-v));
}

__device__ __forceinline__ half8 pack_h8(float4 a, float4 b) {
  half8 r;
  r[0] = (_Float16)a.x; r[1] = (_Float16)a.y; r[2] = (_Float16)a.z; r[3] = (_Float16)a.w;
  r[4] = (_Float16)b.x; r[5] = (_Float16)b.y; r[6] = (_Float16)b.z; r[7] = (_Float16)b.w;
  return r;
}
__device__ __forceinline__ half8 zero_h8() {
  half8 r;
#pragma unroll
  for (int i = 0; i < 8; ++i) r[i] = (_Float16)0.f;
  return r;
}
__device__ __forceinline__ half8 ld8(const _Float16* p) {
  const half4 a = *reinterpret_cast<const half4*>(p);
  const half4 b = *reinterpret_cast<const half4*>(p + 4);
  half8 r;
  r[0] = a[0]; r[1] = a[1]; r[2] = a[2]; r[3] = a[3];
  r[4] = b[0]; r[5] = b[1]; r[6] = b[2]; r[7] = b[3];
  return r;
}

// ---------------------------------------------------------------------------
// Prep: hoist all wg-invariant packing to global f16 tensors.
// ---------------------------------------------------------------------------
__global__ __launch_bounds__(256)
void prep_kernel(const float* __restrict__ x, TeamParams tp0, TeamParams tp1,
                 _Float16* __restrict__ xH, _Float16* __restrict__ WcF,
                 _Float16* __restrict__ WzF, _Float16* __restrict__ WdtF,
                 _Float16* __restrict__ wnH)
{
  const int gid = blockIdx.x * 256 + threadIdx.x;
  const int gsz = gridDim.x * 256;
  for (int i = gid; i < (BBATCH * TSEQ * DMODEL) / 8; i += gsz) {
    const float4 a = *reinterpret_cast<const float4*>(&x[(size_t)i * 8]);
    const float4 b = *reinterpret_cast<const float4*>(&x[(size_t)i * 8 + 4]);
    *reinterpret_cast<half8*>(&xH[(size_t)i * 8]) = pack_h8(a, b);
  }
  for (int i = gid; i < 2 * NHEADS * 4 * CONVD * 2; i += gsz) {
    const int k8 = i & 1;
    const int r = i >> 1;
    const int ch = r % CONVD;
    const int tap = (r / CONVD) & 3;
    const int th = r / (CONVD * 4);
    const int team = th >> 4, h = th & 15;
    const TeamParams P = team ? tp1 : tp0;
    const float cw = P.convw[((size_t)h * CONVD + ch) * 4 + tap];
    const float* wp = &P.Win[((size_t)h * DPROJ + 32 + ch) * HD + k8 * 8];
    half8 v;
#pragma unroll
    for (int j = 0; j < 8; ++j) v[j] = (_Float16)(cw * wp[j]);
    *reinterpret_cast<half8*>(&WcF[(size_t)r * 16 + k8 * 8]) = v;
  }
  for (int i = gid; i < 2 * NHEADS * 32 * 2; i += gsz) {
    const int k8 = i & 1;
    const int r = i >> 1;
    const int row = r & 31;
    const int th = r >> 5;
    const int team = th >> 4, h = th & 15;
    const TeamParams P = team ? tp1 : tp0;
    const float* wp = &P.Win[((size_t)h * DPROJ + row) * HD + k8 * 8];
    half8 v;
#pragma unroll
    for (int j = 0; j < 8; ++j) v[j] = (_Float16)wp[j];
    *reinterpret_cast<half8*>(&WzF[(size_t)r * 16 + k8 * 8]) = v;
  }
  for (int i = gid; i < 2 * NHEADS * 2 * 2; i += gsz) {
    const int k8 = i & 1;
    const int r = i >> 1;
    const int row = r & 1;
    const int th = r >> 1;
    const int team = th >> 4, h = th & 15;
    const TeamParams P = team ? tp1 : tp0;
    const float* wp = &P.Win[((size_t)h * DPROJ + 192 + row) * HD + k8 * 8];
    half8 v;
#pragma unroll
    for (int j = 0; j < 8; ++j) v[j] = (_Float16)wp[j];
    *reinterpret_cast<half8*>(&WdtF[(size_t)r * 16 + k8 * 8]) = v;
  }
  for (int i = gid; i < 2 * NHEADS * HD * DIN / 8; i += gsz) {
    const int dn8 = (i & 3) * 8;
    const int o = (i >> 2) & 15;
    const int th = i >> 6;
    const int team = th >> 4, h = th & 15;
    const TeamParams P = team ? tp1 : tp0;
    half8 v;
#pragma unroll
    for (int j = 0; j < 8; ++j)
      v[j] = (_Float16)(P.Wout[((size_t)h * HD + o) * DIN + dn8 + j] * P.nw[h * DIN + dn8 + j]);
    *reinterpret_cast<half8*>(&wnH[((size_t)th * HD + o) * DIN + dn8]) = v;
  }
}

// ---------------------------------------------------------------------------
// K1: conv-fused in-proj MFMA + SSD chunk computation. LDS packed to exactly
// 20 KB (scan arrays live in row pads) -> 8 wg/CU. Two barriers. convb folded
// into MFMA accumulator init.
// ---------------------------------------------------------------------------
__global__ __launch_bounds__(256, 8)
void k1_proj_ssd(const _Float16* __restrict__ xH, const _Float16* __restrict__ WcF,
                 const _Float16* __restrict__ WdtF, TeamParams tp0, TeamParams tp1,
                 _Float16* __restrict__ Sg, float* __restrict__ Pbuf,
                 float2* __restrict__ cumsg, _Float16* __restrict__ xgC,
                 _Float16* __restrict__ yintra)
{
  __shared__ _Float16 xvT[32][36];       // cols 0..31 data; pad = dtraw (2 f32/row)
  __shared__ _Float16 BmT[64][36];       // pad rows 0..31 = clL; rows 32..63 = dtL2
  __shared__ _Float16 bufA[2][32][36];   // ph1-2: actB ; ph2(wv0-late)+: Gm
  __shared__ _Float16 bufB[32][68];      // ph1-2: actC ; ph3: StL
  __shared__ _Float16 XtL[32][36];       // pad = dwL
  __shared__ _Float16 WXt[32][36];
  // total: 2304+4608+4608+4352+2304+2304 = 20480 B exactly -> 8 wg/CU

  _Float16 (*actB)[68] = reinterpret_cast<_Float16(*)[68]>(&bufA[0][0][0]);
  _Float16 (*actC)[68] = bufB;
  _Float16 (*Gm)[32][36] = bufA;
  _Float16 (*StL)[68] = bufB;

#define DTRAW(t) (reinterpret_cast<float*>(&xvT[t][32]))
#define CLL(t)   (reinterpret_cast<float*>(&BmT[t][32]))
#define DTL2(t)  (reinterpret_cast<float*>(&BmT[32 + (t)][32]))
#define DWL(t)   (reinterpret_cast<float*>(&XtL[t][32]))

  const int tid  = threadIdx.x;
  const int wg   = blockIdx.x;
  const int c    = wg % NCHUNK;
  const int b    = (wg / NCHUNK) % BBATCH;
  const int h    = (wg / (NCHUNK * BBATCH)) % NHEADS;
  const int team = wg / (NCHUNK * BBATCH * NHEADS);
  const TeamParams P = team ? tp1 : tp0;
  const int th = team * NHEADS + h;
  const int c0 = c * CHUNK;
  const size_t base0 = ((size_t)team * NHEADS + h) * BBATCH + b;

  const int lane = tid & 63;
  const int wv   = tid >> 6;
  const int lrow = lane & 31;
  const int kg   = lane >> 5;

  f32x16 z16;
#pragma unroll
  for (int i = 0; i < 16; ++i) z16[i] = 0.0f;

  half8 afr[4];
#pragma unroll
  for (int j = 0; j < 4; ++j) {
    const int tp = c0 + lrow - 3 + j;
    afr[j] = (tp >= 0)
        ? *reinterpret_cast<const half8*>(&xH[((size_t)b * TSEQ + tp) * DMODEL + h * HD + kg * 8])
        : zero_h8();
  }

  auto doTile = [&](int tile) {
    const int ch = tile * 32 + lrow;
    const float cb = P.convb[h * CONVD + ch];
    f32x16 acc;
#pragma unroll
    for (int i = 0; i < 16; ++i) acc[i] = cb;   // convb folded into C-operand
#pragma unroll
    for (int j = 0; j < 4; ++j) {
      const half8 bf = *reinterpret_cast<const half8*>(
          &WcF[((size_t)(th * 4 + j) * CONVD + ch) * 16 + kg * 8]);
      acc = __builtin_amdgcn_mfma_f32_32x32x16_f16(afr[j], bf, acc, 0, 0, 0);
    }
    _Float16 sv[16];
#pragma unroll
    for (int rg = 0; rg < 16; ++rg) {
      const float vv = acc[rg];
      sv[rg] = (_Float16)(vv * sigm(vv));
    }
    if (tile == 0) {
#pragma unroll
      for (int m = 0; m < 4; ++m) {
        half4 v; v[0] = sv[4*m]; v[1] = sv[4*m+1]; v[2] = sv[4*m+2]; v[3] = sv[4*m+3];
        *reinterpret_cast<half4*>(&xvT[lrow][4 * kg + 8 * m]) = v;
      }
    } else if (tile <= 2) {
      const int n = ch - 32;
#pragma unroll
      for (int m = 0; m < 4; ++m) {
        half4 v; v[0] = sv[4*m]; v[1] = sv[4*m+1]; v[2] = sv[4*m+2]; v[3] = sv[4*m+3];
        *reinterpret_cast<half4*>(&BmT[n][4 * kg + 8 * m]) = v;
      }
#pragma unroll
      for (int rg = 0; rg < 16; ++rg) {
        const int t = (rg & 3) + 8 * (rg >> 2) + 4 * kg;
        actB[t][n] = sv[rg];
      }
    } else {
      const int n = ch - 96;
#pragma unroll
      for (int rg = 0; rg < 16; ++rg) {
        const int t = (rg & 3) + 8 * (rg >> 2) + 4 * kg;
        actC[t][n] = sv[rg];
      }
    }
  };

  // ================= phase 1 ===============================================
  if (wv == 0) {
    doTile(0);
  } else if (wv == 1) {
    doTile(1);
  } else if (wv == 2) {
    doTile(2);
    // dt MFMA + wave-local scan (no cross-wave dependency)
    half8 bf5 = zero_h8();
    if (lrow < 2)
      bf5 = *reinterpret_cast<const half8*>(&WdtF[((size_t)th * 2 + lrow) * 16 + kg * 8]);
    const f32x16 a5 = __builtin_amdgcn_mfma_f32_32x32x16_f16(afr[3], bf5, z16, 0, 0, 0);
    if (lrow < 2) {
#pragma unroll
      for (int rg = 0; rg < 16; ++rg) {
        const int t = (rg & 3) + 8 * (rg >> 2) + 4 * kg;
        DTRAW(t)[lrow] = a5[rg];
      }
    }
    // same-wave LDS RAW: compiler inserts lgkmcnt wait; no barrier needed
    {
      const int t = lane & 31, hi = lane >> 5;
      const float dtbias = P.dtb[h * NHIN + hi];
      const float Ah = -__expf(P.Alog[h * NHIN + hi]);
      const float raw = DTRAW(t)[hi] + dtbias;
      const float dtv = (raw > 20.f) ? raw : __logf(1.0f + __expf(raw));
      float s = dtv * Ah;
#pragma unroll
      for (int d = 1; d < 32; d <<= 1) {
        const float v = __shfl_up(s, d, 32);
        if (t >= d) s += v;
      }
      const float cl31 = __shfl(s, 31, 32);
      const float w = __expf(cl31 - s);
      const float ecl = __expf(s);
      CLL(t)[hi] = s;
      DTL2(t)[hi] = dtv;
      DWL(t)[hi] = w * dtv;
      const float eo = __shfl(ecl, (lane & 31) + 32, 64);
      if (lane < 32) cumsg[(size_t)wg * CHUNK + t] = make_float2(ecl, eo);
      if (t == 31) Pbuf[(base0 * NCHUNK + c) * NHIN + hi] = ecl;
    }
  } else {
    doTile(3);
    doTile(4);
  }
  __syncthreads();   // B1

  // ================= phase 2 ===============================================
  if (wv == 0) {
    // G = C·B^T, then mask in the SAME wave (clL ready at B1)
    f32x16 g = z16;
#pragma unroll
    for (int kk = 0; kk < 4; ++kk) {
      const half8 af = ld8(&actC[lrow][kk * 16 + kg * 8]);
      const half8 bf = ld8(&actB[lrow][kk * 16 + kg * 8]);
      g = __builtin_amdgcn_mfma_f32_32x32x16_f16(af, bf, g, 0, 0, 0);
    }
    const float cls0 = CLL(lrow)[0], cls1 = CLL(lrow)[1];
#pragma unroll
    for (int rg = 0; rg < 16; ++rg) {
      const int t = (rg & 3) + 8 * (rg >> 2) + 4 * kg;
      const float gg = g[rg];
      float l0 = 0.f, l1 = 0.f;
      if (lrow <= t) { l0 = __expf(CLL(t)[0] - cls0); l1 = __expf(CLL(t)[1] - cls1); }
      Gm[0][t][lrow] = (_Float16)(l0 * gg);
      Gm[1][t][lrow] = (_Float16)(l1 * gg);
    }
  } else if (wv == 1 || wv == 2) {
    const int idx = tid - 64;
    const int ch = idx & 31, tq = idx >> 5;
    const int hi = ch >> 4;
#pragma unroll
    for (int hh = 0; hh < 2; ++hh) {
      const int t4 = tq * 8 + hh * 4;
      const half4 xv4 = *reinterpret_cast<const half4*>(&xvT[ch][t4]);
      half4 xt, wx;
#pragma unroll
      for (int i = 0; i < 4; ++i) {
        const int t = t4 + i;
        const float xv = (float)xv4[i];
        xt[i] = (_Float16)(DTL2(t)[hi] * xv);
        wx[i] = (_Float16)(DWL(t)[hi] * xv);
      }
      *reinterpret_cast<half4*>(&XtL[ch][t4]) = xt;
      *reinterpret_cast<half4*>(&WXt[ch][t4]) = wx;
    }
  } else {
    // wv3: xgC store (reads actC)
#pragma unroll
    for (int k = 0; k < 8; ++k) {
      const int idx = lane + k * 64;
      const int t = idx >> 4, c4 = (idx & 15) * 4;
      *reinterpret_cast<ushort4*>(&xgC[(size_t)wg * (CHUNK * DST) + t * DST + c4]) =
          *reinterpret_cast<const ushort4*>(&actC[t][c4]);
    }
  }
  __syncthreads();   // B2

  // ================= phase 3 ===============================================
  if (wv == 0 || wv == 3) {
    const int hi = (wv == 0) ? 0 : 1;
    const half8 xb0 = ld8(&XtL[lrow][kg * 8]);
    const half8 xb1 = ld8(&XtL[lrow][16 + kg * 8]);
    f32x16 acc = z16;
    acc = __builtin_amdgcn_mfma_f32_32x32x16_f16(ld8(&Gm[hi][lrow][kg * 8]), xb0, acc, 0, 0, 0);
    acc = __builtin_amdgcn_mfma_f32_32x32x16_f16(ld8(&Gm[hi][lrow][16 + kg * 8]), xb1, acc, 0, 0, 0);
    if ((lrow >> 4) == hi) {
      const float Dp = P.Dp[h * NHIN + hi];
      _Float16* yo = &yintra[(size_t)wg * (CHUNK * DIN)];
#pragma unroll
      for (int rg = 0; rg < 16; ++rg) {
        const int t = (rg & 3) + 8 * (rg >> 2) + 4 * kg;
        yo[t * DIN + lrow] = (_Float16)(acc[rg] + Dp * (float)xvT[lrow][t]);
      }
    }
  } else {
    const int nhalf = (wv - 1) * 32;
    const half8 wa0 = ld8(&WXt[lrow][kg * 8]);
    const half8 wa1 = ld8(&WXt[lrow][16 + kg * 8]);
    f32x16 acc = z16;
    acc = __builtin_amdgcn_mfma_f32_32x32x16_f16(
        wa0, ld8(&BmT[nhalf + lrow][kg * 8]), acc, 0, 0, 0);
    acc = __builtin_amdgcn_mfma_f32_32x32x16_f16(
        wa1, ld8(&BmT[nhalf + lrow][16 + kg * 8]), acc, 0, 0, 0);
#pragma unroll
    for (int rg = 0; rg < 16; ++rg) {
      const int m = (rg & 3) + 8 * (rg >> 2) + 4 * kg;
      StL[m][nhalf + lrow] = (_Float16)acc[rg];
    }
    // same-wave LDS RAW (own nhalf columns) -> no barrier needed
    const size_t base2 = (base0 * NCHUNK + c) * (NHIN * HD * DST);
#pragma unroll
    for (int k = 0; k < 4; ++k) {
      const int idx = lane + k * 64;
      const int row = idx >> 3, c4 = (idx & 7) * 4 + nhalf;
      *reinterpret_cast<ushort4*>(&Sg[base2 + row * DST + c4]) =
          *reinterpret_cast<const ushort4*>(&StL[row][c4]);
    }
  }
#undef DTRAW
#undef CLL
#undef DTL2
#undef DWL
}

// ---------------------------------------------------------------------------
// Carry: 256 wgs x 64 threads; 8-deep prefetch.
// ---------------------------------------------------------------------------
__global__ __launch_bounds__(64)
void carry_kernel(_Float16* __restrict__ Sg, const float* __restrict__ Pbuf)
{
  const int wg = blockIdx.x;
  const int q = wg & 3;
  const int rest = wg >> 2;
  const int b = rest % BBATCH;
  const int h = (rest / BBATCH) % NHEADS;
  const int team = rest / (BBATCH * NHEADS);
  const int lane = threadIdx.x;
  const int off = q * 512 + lane * 8;
  const int hi = q >> 1;
  const size_t base0 = ((size_t)team * NHEADS + h) * BBATCH + b;

  float hc[8] = {0, 0, 0, 0, 0, 0, 0, 0};
  for (int cb = 0; cb < NCHUNK; cb += 8) {
    half8 a[8];
    float Pv[8];
#pragma unroll
    for (int j = 0; j < 8; ++j) {
      const size_t sb = (base0 * NCHUNK + cb + j) * (NHIN * HD * DST) + off;
      a[j] = *reinterpret_cast<const half8*>(&Sg[sb]);
      Pv[j] = Pbuf[(base0 * NCHUNK + cb + j) * NHIN + hi];
    }
#pragma unroll
    for (int j = 0; j < 8; ++j) {
      const size_t sb = (base0 * NCHUNK + cb + j) * (NHIN * HD * DST) + off;
      half8 o;
#pragma unroll
      for (int k = 0; k < 8; ++k) o[k] = (_Float16)hc[k];
      *reinterpret_cast<half8*>(&Sg[sb]) = o;
#pragma unroll
      for (int k = 0; k < 8; ++k) hc[k] = fmaf(Pv[j], hc[k], (float)a[j][k]);
    }
  }
}

// ---------------------------------------------------------------------------
// K3 fused: C·H_in + z MFMAs, gate+rms (-> f16), MFMA out-proj, diff, stats.
// ---------------------------------------------------------------------------
__global__ __launch_bounds__(256)
void k3_fused(const _Float16* __restrict__ Sg, const float2* __restrict__ cumsg,
              const _Float16* __restrict__ xgC, const _Float16* __restrict__ xH,
              const _Float16* __restrict__ WzF, const _Float16* __restrict__ wnH,
              const _Float16* __restrict__ yintra, const float* __restrict__ lam,
              float* __restrict__ diffb, float2* __restrict__ pstat)
{
  __shared__ float    ysh[2][CHUNK][YS];
  __shared__ float    cums2[2][CHUNK][2];
  __shared__ _Float16 zsh[2][32][40];
  __shared__ _Float16 ygH[2][32][36];
  __shared__ float    youtL[2][CHUNK][20];
  __shared__ float    red2[8];

  const int tid  = threadIdx.x;
  const int wg   = blockIdx.x;
  const int c    = wg % NCHUNK;
  const int b    = (wg / NCHUNK) % BBATCH;
  const int h    = wg / (NCHUNK * BBATCH);
  const int c0 = c * CHUNK;
  const int lane = tid & 63;
  const int wv   = tid >> 6;
  const int lrow = lane & 31;
  const int kg   = lane >> 5;

  const size_t wgT0 = (((size_t)0 * NHEADS + h) * BBATCH + b) * NCHUNK + c;
  const size_t wgT1 = (((size_t)1 * NHEADS + h) * BBATCH + b) * NCHUNK + c;

  f32x16 acc;
  if (wv < 2) {
    const size_t wgT = wv ? wgT1 : wgT0;
    const _Float16* ca = &xgC[wgT * (CHUNK * DST) + (size_t)lrow * DST + kg * 8];
    const _Float16* hb = &Sg[wgT * (NHIN * HD * DST) + (size_t)lrow * DST + kg * 8];
#pragma unroll
    for (int i = 0; i < 16; ++i) acc[i] = 0.0f;
    acc = __builtin_amdgcn_mfma_f32_32x32x16_f16(
        *reinterpret_cast<const half8*>(ca), *reinterpret_cast<const half8*>(hb), acc, 0, 0, 0);
    acc = __builtin_amdgcn_mfma_f32_32x32x16_f16(
        *reinterpret_cast<const half8*>(ca + 16), *reinterpret_cast<const half8*>(hb + 16), acc, 0, 0, 0);
    acc = __builtin_amdgcn_mfma_f32_32x32x16_f16(
        *reinterpret_cast<const half8*>(ca + 32), *reinterpret_cast<const half8*>(hb + 32), acc, 0, 0, 0);
    acc = __builtin_amdgcn_mfma_f32_32x32x16_f16(
        *reinterpret_cast<const half8*>(ca + 48), *reinterpret_cast<const half8*>(hb + 48), acc, 0, 0, 0);
  } else {
    const int team = wv - 2;
    const int th = team * NHEADS + h;
    const half8 afr = *reinterpret_cast<const half8*>(
        &xH[((size_t)b * TSEQ + c0 + lrow) * DMODEL + h * HD + kg * 8]);
    const half8 bfr = *reinterpret_cast<const half8*>(
        &WzF[((size_t)th * 32 + lrow) * 16 + kg * 8]);
    f32x16 zacc;
#pragma unroll
    for (int i = 0; i < 16; ++i) zacc[i] = 0.0f;
    zacc = __builtin_amdgcn_mfma_f32_32x32x16_f16(afr, bfr, zacc, 0, 0, 0);
#pragma unroll
    for (int rg = 0; rg < 16; ++rg) {
      const int t = (rg & 3) + 8 * (rg >> 2) + 4 * kg;
      const float v = zacc[rg];
      zsh[team][t][lrow] = (_Float16)(v * sigm(v));
    }
  }

  {
    const int tm = tid >> 7, li = tid & 127;
    const int t = li >> 2, c8 = (li & 3) * 8;
    const size_t wgT = tm ? wgT1 : wgT0;
    const half8 v = *reinterpret_cast<const half8*>(&yintra[wgT * (CHUNK * DIN) + li * 8]);
#pragma unroll
    for (int j = 0; j < 8; ++j) ysh[tm][t][c8 + j] = (float)v[j];
  }
  if (tid < 64) {
    const int tm = tid >> 5, t = tid & 31;
    const size_t wgT = tm ? wgT1 : wgT0;
    const float2 v = cumsg[wgT * CHUNK + t];
    cums2[tm][t][0] = v.x; cums2[tm][t][1] = v.y;
  }
  __syncthreads();   // B1

  if (wv < 2) {
    const int team = wv;
    const int hi = lrow >> 4;
#pragma unroll
    for (int rg = 0; rg < 16; ++rg) {
      const int t = (rg & 3) + 8 * (rg >> 2) + 4 * kg;
      ysh[team][t][lrow] = fmaf(cums2[team][t][hi], acc[rg], ysh[team][t][lrow]);
    }
  }
  __syncthreads();   // B2

  {
    const int tm = tid >> 7, l = tid & 127;
    const int q = l & 3, tl = l >> 2;
    const int dn0 = q * 8;
    float yg[8];
    float ss = 0.0f;
#pragma unroll
    for (int j = 0; j < 8; ++j) {
      const float g = ysh[tm][tl][dn0 + j] * (float)zsh[tm][tl][dn0 + j];
      yg[j] = g;
      ss += g * g;
    }
    ss += __shfl_xor(ss, 1, 4);
    ss += __shfl_xor(ss, 2, 4);
    const float rms = rsqrtf(ss * (1.0f / DIN) + 1e-5f);
    half4 o0, o1;
#pragma unroll
    for (int j = 0; j < 4; ++j) o0[j] = (_Float16)(yg[j] * rms);
#pragma unroll
    for (int j = 0; j < 4; ++j) o1[j] = (_Float16)(yg[4 + j] * rms);
    *reinterpret_cast<half4*>(&ygH[tm][tl][dn0]) = o0;
    *reinterpret_cast<half4*>(&ygH[tm][tl][dn0 + 4]) = o1;
  }
  __syncthreads();   // B3

  if (wv < 2) {
    const int tm = wv;
    const int th2 = tm * NHEADS + h;
    const half8 af0 = ld8(&ygH[tm][lrow][kg * 8]);
    const half8 af1 = ld8(&ygH[tm][lrow][16 + kg * 8]);
    half8 bf0 = zero_h8(), bf1 = zero_h8();
    if (lrow < 16) {
      const _Float16* wp = &wnH[((size_t)th2 * HD + lrow) * DIN];
      bf0 = *reinterpret_cast<const half8*>(wp + kg * 8);
      bf1 = *reinterpret_cast<const half8*>(wp + 16 + kg * 8);
    }
    f32x16 oacc;
#pragma unroll
    for (int i = 0; i < 16; ++i) oacc[i] = 0.0f;
    oacc = __builtin_amdgcn_mfma_f32_32x32x16_f16(af0, bf0, oacc, 0, 0, 0);
    oacc = __builtin_amdgcn_mfma_f32_32x32x16_f16(af1, bf1, oacc, 0, 0, 0);
    if (lrow < 16) {
#pragma unroll
      for (int rg = 0; rg < 16; ++rg) {
        const int t = (rg & 3) + 8 * (rg >> 2) + 4 * kg;
        youtL[tm][t][lrow] = oacc[rg];
      }
    }
  }
  __syncthreads();   // B4

  float s = 0.0f, s2 = 0.0f;
  if (tid < 128) {
    const int t = tid >> 2, hd0 = (tid & 3) * 4;
    const float4 l4 = *reinterpret_cast<const float4*>(&lam[h * HD + hd0]);
    const float* y0 = &youtL[0][t][hd0];
    const float* y1 = &youtL[1][t][hd0];
    float4 d;
    d.x = y0[0] - l4.x * y1[0];
    d.y = y0[1] - l4.y * y1[1];
    d.z = y0[2] - l4.z * y1[2];
    d.w = y0[3] - l4.w * y1[3];
    *reinterpret_cast<float4*>(
        &diffb[(((size_t)(h * BBATCH + b)) * TSEQ + c0 + t) * HD + hd0]) = d;
    s = d.x + d.y + d.z + d.w;
    s2 = d.x * d.x + d.y * d.y + d.z * d.z + d.w * d.w;
  }
#pragma unroll
  for (int off = 1; off < 64; off <<= 1) {
    s += __shfl_xor(s, off);
    s2 += __shfl_xor(s2, off);
  }
  if (lane == 0) { red2[wv * 2] = s; red2[wv * 2 + 1] = s2; }
  __syncthreads();
  if (tid == 0) pstat[wg] = make_float2(red2[0] + red2[2], red2[1] + red2[3]);
}

// ---------------------------------------------------------------------------
// Final (MFMA): stats reduce + groupnorm-apply (f16) + [32x256]x[256x256]
// f16 MFMA GEMM + bias + residual.
// ---------------------------------------------------------------------------
#define NFW (BBATCH * (TSEQ / 32) * 2)   // 256
__global__ __launch_bounds__(256)
void final_mfma(const float* __restrict__ x, const float* __restrict__ diffb,
                const float2* __restrict__ pstat, const float* __restrict__ gnw,
                const float* __restrict__ gnb, const float* __restrict__ projw,
                const float* __restrict__ projb, float* __restrict__ out)
{
  __shared__ _Float16 ndH[32][268];
  __shared__ float statL[NHEADS][2];

  const int wg = blockIdx.x;
  const int chalf = wg & 1;
  const int tt = (wg >> 1) & 63;
  const int b = wg >> 7;
  const int t0 = tt * 32;
  const int tid = threadIdx.x;
  const int lane = tid & 63;
  const int wv = tid >> 6;

  {
    const int h = tid >> 4, k0 = tid & 15;
    float s = 0.0f, s2 = 0.0f;
    for (int k = k0; k < NCHUNK; k += 16) {
      const float2 v = pstat[((size_t)h * BBATCH + b) * NCHUNK + k];
      s += v.x; s2 += v.y;
    }
    s += __shfl_xor(s, 1, 16);  s2 += __shfl_xor(s2, 1, 16);
    s += __shfl_xor(s, 2, 16);  s2 += __shfl_xor(s2, 2, 16);
    s += __shfl_xor(s, 4, 16);  s2 += __shfl_xor(s2, 4, 16);
    s += __shfl_xor(s, 8, 16);  s2 += __shfl_xor(s2, 8, 16);
    if (k0 == 0) {
      const float inv = 1.0f / (TSEQ * HD);
      const float mean = s * inv;
      const float var = s2 * inv - mean * mean;
      statL[h][0] = mean;
      statL[h][1] = rsqrtf(var + 1e-5f);
    }
  }
  __syncthreads();

  {
    const int d = tid, h = d >> 4, hd = d & 15;
    const float mean = statL[h][0];
    const float rstd = statL[h][1];
    const float g = gnw[d];
    const float be = gnb[d];
    const float* dp = &diffb[((size_t)(h * BBATCH + b) * TSEQ + t0) * HD + hd];
#pragma unroll
    for (int t = 0; t < 32; ++t)
      ndH[t][d] = (_Float16)((dp[t * HD] - mean) * rstd * g + be);
  }
  __syncthreads();

  const int lrow = lane & 31, kg = lane >> 5;
  const int n0 = chalf * 128 + wv * 32;
  const int d = n0 + lrow;
  f32x16 acc;
#pragma unroll
  for (int i = 0; i < 16; ++i) acc[i] = 0.0f;
  const float* wp0 = &projw[(size_t)d * DMODEL + kg * 8];
#pragma unroll
  for (int kt = 0; kt < DMODEL; kt += 16) {
    const half8 af = ld8(&ndH[lrow][kt + kg * 8]);
    const half8 bf = pack_h8(*reinterpret_cast<const float4*>(wp0 + kt),
                             *reinterpret_cast<const float4*>(wp0 + kt + 4));
    acc = __builtin_amdgcn_mfma_f32_32x32x16_f16(af, bf, acc, 0, 0, 0);
  }

  const float pb = projb[d];
#pragma unroll
  for (int rg = 0; rg < 16; ++rg) {
    const int t = (rg & 3) + 8 * (rg >> 2) + 4 * kg;
    const size_t o = ((size_t)b * TSEQ + t0 + t) * DMODEL + d;
    out[o] = x[o] + pb + acc[rg];
  }
}

// ---------------------------------------------------------------------------
extern "C" void kernel_launch(void* const* d_in, const int* in_sizes, int n_in,
                              void* d_out, int out_size, void* d_ws, size_t ws_size,
                              hipStream_t stream)
{
  const float* x = (const float*)d_in[0];
  TeamParams tp0 { (const float*)d_in[1], (const float*)d_in[2], (const float*)d_in[3],
                   (const float*)d_in[4], (const float*)d_in[5], (const float*)d_in[6],
                   (const float*)d_in[7], (const float*)d_in[8] };
  TeamParams tp1 { (const float*)d_in[9], (const float*)d_in[10], (const float*)d_in[11],
                   (const float*)d_in[12], (const float*)d_in[13], (const float*)d_in[14],
                   (const float*)d_in[15], (const float*)d_in[16] };
  const float* lam   = (const float*)d_in[17];
  const float* gnw   = (const float*)d_in[18];
  const float* gnb   = (const float*)d_in[19];
  const float* projw = (const float*)d_in[20];
  const float* projb = (const float*)d_in[21];

  // ws layout (bytes):
  //   Sg      @ 0           16,777,216
  //   Pbuf    @ 16,777,216      32,768
  //   cumsg   @ 16,809,984   1,048,576
  //   xgC     @ 17,858,560  16,777,216
  //   yintra  @ 34,635,776   8,388,608
  //   diffb   @ 43,024,384   4,194,304
  //   pstat   @ 47,218,688      16,384
  //   xH      @ 47,235,072   2,097,152
  //   WcF     @ 49,332,224     655,360
  //   WzF     @ 49,987,584      32,768
  //   WdtF    @ 50,020,352       2,048
  //   wnH     @ 50,022,400      32,768   (total ~50.1 MB)
  char* wsb = (char*)d_ws;
  _Float16* Sg    = (_Float16*)wsb;
  float* Pbuf     = (float*)(wsb + 16777216);
  float2* cumsg   = (float2*)(wsb + 16809984);
  _Float16* xgC   = (_Float16*)(wsb + 17858560);
  _Float16* yintra= (_Float16*)(wsb + 34635776);
  float* diffb    = (float*)(wsb + 43024384);
  float2* pstat   = (float2*)(wsb + 47218688);
  _Float16* xH    = (_Float16*)(wsb + 47235072);
  _Float16* WcF   = (_Float16*)(wsb + 49332224);
  _Float16* WzF   = (_Float16*)(wsb + 49987584);
  _Float16* WdtF  = (_Float16*)(wsb + 50020352);
  _Float16* wnH   = (_Float16*)(wsb + 50022400);

  prep_kernel<<<dim3(320), dim3(256), 0, stream>>>(x, tp0, tp1, xH, WcF, WzF, WdtF, wnH);
  k1_proj_ssd<<<dim3(NWG), dim3(256), 0, stream>>>(xH, WcF, WdtF, tp0, tp1, Sg, Pbuf, cumsg, xgC, yintra);
  carry_kernel<<<dim3(2 * NHEADS * BBATCH * 4), dim3(64), 0, stream>>>(Sg, Pbuf);
  k3_fused<<<dim3(NWG3), dim3(256), 0, stream>>>(Sg, cumsg, xgC, xH, WzF, wnH, yintra, lam, diffb, pstat);
  final_mfma<<<dim3(NFW), dim3(256), 0, stream>>>(
      x, diffb, pstat, gnw, gnb, projw, projb, (float*)d_out);
}